// Round 2
// baseline (1640.191 us; speedup 1.0000x reference)
//
#include <hip/hip_runtime.h>

// SAGEEncoder v2: lane=node mapping, scalar-load weights (no readlane),
// lockstep gather, LDS-overlay pools. fp32 throughout.

#define INFF 3.402823466e38f

// ---- edge dtype detection: int64 iff the first 32 odd u32 slots are all zero ----
__global__ void detect_idx64(const unsigned* __restrict__ e, int* __restrict__ flag) {
  if (threadIdx.x == 0 && blockIdx.x == 0) {
    int is64 = 1;
    for (int i = 0; i < 32; ++i)
      if (e[2 * i + 1] != 0u) { is64 = 0; break; }
    *flag = is64;
  }
}

__device__ __forceinline__ int edge_val(const void* e, int is64, long long idx) {
  if (is64) return (int)((const long long*)e)[idx];
  return ((const int*)e)[idx];
}

__global__ void count_deg(const void* __restrict__ edges, const int* __restrict__ flag,
                          int* __restrict__ deg, int nE) {
  int is64 = *flag;
  long long E = nE;
  for (int i = blockIdx.x * blockDim.x + threadIdx.x; i < nE; i += gridDim.x * blockDim.x) {
    int dst = edge_val(edges, is64, E + i);
    atomicAdd(&deg[dst], 1);
  }
}

__global__ void scan_deg(const int* __restrict__ deg, int* __restrict__ row_start, int n) {
  __shared__ int sums[1024];
  int t = threadIdx.x;
  int chunk = (n + 1023) >> 10;
  int lo = t * chunk;
  int hi = min(lo + chunk, n);
  int s = 0;
  for (int i = lo; i < hi; ++i) s += deg[i];
  sums[t] = s;
  __syncthreads();
  for (int off = 1; off < 1024; off <<= 1) {
    int v = (t >= off) ? sums[t - off] : 0;
    __syncthreads();
    sums[t] += v;
    __syncthreads();
  }
  int run = (t > 0) ? sums[t - 1] : 0;
  for (int i = lo; i < hi; ++i) { row_start[i] = run; run += deg[i]; }
  if (t == 1023) row_start[n] = sums[1023];
}

__global__ void fill_csr(const void* __restrict__ edges, const int* __restrict__ flag,
                         const int* __restrict__ row_start, int* __restrict__ cursor,
                         int* __restrict__ csr_src, int nE) {
  int is64 = *flag;
  long long E = nE;
  for (int i = blockIdx.x * blockDim.x + threadIdx.x; i < nE; i += gridDim.x * blockDim.x) {
    int src = edge_val(edges, is64, i);
    int dst = edge_val(edges, is64, E + i);
    int p = atomicAdd(&cursor[dst], 1);
    csr_src[row_start[dst] + p] = src;
  }
}

// ---- precompute transposed weights into workspace ----
// wt[l][k][f]: k<128 -> wl[l][f][k]; k in 128..191 -> wr[l][f][k-128]
// awt[k][f] = aw[f][k]; w1t[k][p] = w1[p][k]; w2t[k][f] = w2[f][k]
__global__ void prep_weights(const float* __restrict__ wl, const float* __restrict__ wr,
                             const float* __restrict__ aw, const float* __restrict__ w1,
                             const float* __restrict__ w2,
                             float* __restrict__ wt, float* __restrict__ awt,
                             float* __restrict__ w1t, float* __restrict__ w2t, int nl) {
  int i = blockIdx.x * 256 + threadIdx.x;
  int tot_wt = nl * 192 * 64;
  if (i < tot_wt) {
    int l = i / (192 * 64);
    int r = i % (192 * 64);
    int k = r >> 6, f = r & 63;
    wt[i] = (k < 128) ? wl[(size_t)l * 64 * 128 + f * 128 + k]
                      : wr[(size_t)l * 64 * 64 + f * 64 + (k - 128)];
  } else {
    int j = i - tot_wt;
    if (j < 64 * 64) {
      int k = j >> 6, f = j & 63;
      awt[j] = aw[f * 64 + k];
    } else if (j < 64 * 64 + 64 * 256) {
      int q = j - 64 * 64;
      int k = q >> 8, p = q & 255;
      w1t[q] = w1[p * 64 + k];
    } else if (j < 64 * 64 + 64 * 256 + 256 * 64) {
      int q = j - 64 * 64 - 64 * 256;
      int k = q >> 6, f = q & 63;
      w2t[q] = w2[f * 256 + k];
    }
  }
}

// ---- fused SAGE layer: aggregation -> GEMM -> LN -> +residual -> SiLU ----
// Block: 256 threads (4 waves), 64 nodes. Phase2: lane=node, wave owns 16 features.
template <bool FIRST>
__global__ __launch_bounds__(256) void sage_layer(
    const float* __restrict__ in, float* __restrict__ out,
    const int* __restrict__ row_start, const int* __restrict__ csr_src,
    const float* __restrict__ wt,    // [192][64]
    const float* __restrict__ awt,   // [64][64]
    const float* __restrict__ bl, const float* __restrict__ ab,
    const float* __restrict__ lng, const float* __restrict__ lnb,
    int nN) {
  __shared__ float lds[64 * 200 + 512];  // agg[64][200] (+x cols 128..191), ln1[256], ln2[256]
  float* agg = lds;
  float* ln1 = lds + 12800;
  float* ln2 = ln1 + 256;

  int t = threadIdx.x;
  int wv = t >> 6, lane = t & 63;
  int base = blockIdx.x * 64;

  // Phase 1: aggregation. Wave handles 16 nodes, 4 at a time lockstep (8 loads in flight).
  for (int g = 0; g < 4; ++g) {
    int nloc0 = wv * 16 + g * 4;
    int e0[4], dg[4];
#pragma unroll
    for (int j = 0; j < 4; ++j) {
      int nj = base + nloc0 + j;
      bool ok = nj < nN;
      int a = ok ? row_start[nj] : 0;
      int b = ok ? row_start[nj + 1] : 0;
      e0[j] = a;
      dg[j] = b - a;
    }
    int mm = max(max(dg[0], dg[1]), max(dg[2], dg[3]));
    float mx[4], sm[4];
#pragma unroll
    for (int j = 0; j < 4; ++j) { mx[j] = -INFF; sm[j] = 0.f; }
#pragma unroll 2
    for (int tt = 0; tt < mm; ++tt) {
      int s[4];
#pragma unroll
      for (int j = 0; j < 4; ++j) s[j] = (tt < dg[j]) ? csr_src[e0[j] + tt] : 0;
      float v[4];
#pragma unroll
      for (int j = 0; j < 4; ++j) v[j] = in[(size_t)s[j] * 64 + lane];
#pragma unroll
      for (int j = 0; j < 4; ++j) {
        bool upd = tt < dg[j];
        mx[j] = upd ? fmaxf(mx[j], v[j]) : mx[j];
        sm[j] += upd ? v[j] : 0.f;
      }
    }
#pragma unroll
    for (int j = 0; j < 4; ++j) {
      int nl_ = nloc0 + j;
      int nj = base + nl_;
      float xv = (nj < nN) ? in[(size_t)nj * 64 + lane] : 0.f;
      agg[nl_ * 200 + lane] = (dg[j] > 0) ? mx[j] : 0.f;
      agg[nl_ * 200 + 64 + lane] = sm[j] / fmaxf((float)dg[j], 1.f);
      agg[nl_ * 200 + 128 + lane] = xv;
    }
  }
  __syncthreads();

  // Phase 2: GEMM. lane = node, wave owns features f0..f0+15.
  int f0 = __builtin_amdgcn_readfirstlane(wv * 16);
  float acc[16], accr[16];
#pragma unroll
  for (int i = 0; i < 16; ++i) { acc[i] = 0.f; accr[i] = 0.f; }
  for (int kc = 0; kc < 192; kc += 4) {
    float4 av = *(const float4*)&agg[lane * 200 + kc];
    float a4[4] = {av.x, av.y, av.z, av.w};
#pragma unroll
    for (int q = 0; q < 4; ++q) {
      int k = kc + q;
      const float* wrow = wt + k * 64 + f0;
#pragma unroll
      for (int i = 0; i < 16; ++i) acc[i] = fmaf(a4[q], wrow[i], acc[i]);
      if (FIRST) {
        if (k >= 128) {
          const float* arow = awt + (k - 128) * 64 + f0;
#pragma unroll
          for (int i = 0; i < 16; ++i) accr[i] = fmaf(a4[q], arow[i], accr[i]);
        }
      }
    }
  }

  // Phase 3: bias, LN (cross-wave reduce), residual, SiLU.
#pragma unroll
  for (int i = 0; i < 16; ++i) acc[i] += bl[f0 + i];
  float s1 = 0.f, s2 = 0.f;
#pragma unroll
  for (int i = 0; i < 16; ++i) { s1 += acc[i]; s2 = fmaf(acc[i], acc[i], s2); }
  ln1[wv * 64 + lane] = s1;
  ln2[wv * 64 + lane] = s2;
  __syncthreads();
  float t1 = (ln1[lane] + ln1[64 + lane]) + (ln1[128 + lane] + ln1[192 + lane]);
  float t2 = (ln2[lane] + ln2[64 + lane]) + (ln2[128 + lane] + ln2[192 + lane]);
  float mean = t1 * 0.015625f;
  float var = t2 * 0.015625f - mean * mean;
  float rs = rsqrtf(var + 1e-5f);

  float res[16];
  if (FIRST) {
#pragma unroll
    for (int i = 0; i < 16; ++i) res[i] = accr[i] + ab[f0 + i];
  } else {
#pragma unroll
    for (int q = 0; q < 4; ++q) {
      float4 rv = *(const float4*)&agg[lane * 200 + 128 + f0 + 4 * q];
      res[4 * q + 0] = rv.x; res[4 * q + 1] = rv.y; res[4 * q + 2] = rv.z; res[4 * q + 3] = rv.w;
    }
  }
  float y[16];
#pragma unroll
  for (int i = 0; i < 16; ++i) {
    float v = (acc[i] - mean) * rs * lng[f0 + i] + lnb[f0 + i] + res[i];
    y[i] = v / (1.f + __expf(-v));
  }
  // transpose via LDS (reuse agg cols 0..63) then coalesced store
#pragma unroll
  for (int q = 0; q < 4; ++q) {
    float4 w = {y[4 * q], y[4 * q + 1], y[4 * q + 2], y[4 * q + 3]};
    *(float4*)&agg[lane * 200 + f0 + 4 * q] = w;
  }
  __syncthreads();
#pragma unroll
  for (int r = 0; r < 16; ++r) {
    int nl_ = r * 4 + wv;
    int nj = base + nl_;
    if (nj < nN) out[(size_t)nj * 64 + lane] = agg[nl_ * 200 + lane];
  }
}

// ---- MLP head: silu(h@w1.T+b1) -> LN(256) -> @w2.T+b2 ----
// Block: 512 threads (8 waves), 64 nodes. lane=node throughout.
__global__ __launch_bounds__(512) void mlp_head(
    const float* __restrict__ in, float* __restrict__ out,
    const float* __restrict__ w1t,  // [64][256]
    const float* __restrict__ b1,
    const float* __restrict__ lng, const float* __restrict__ lnb,
    const float* __restrict__ w2t,  // [256][64]
    const float* __restrict__ b2, int nN) {
  __shared__ float pool[64 * 272 + 1024];  // h[64][80] / u[64][272] / trans[64][80] overlaid; ln at end
  float* ln1 = pool + 17408;
  float* ln2 = ln1 + 512;

  int t = threadIdx.x;
  int wv = t >> 6, lane = t & 63;
  int base = blockIdx.x * 64;

  // stage h coalesced: h[n*80+f]
#pragma unroll
  for (int r = 0; r < 8; ++r) {
    int n = r * 8 + wv;
    int nj = base + n;
    pool[n * 80 + lane] = (nj < nN) ? in[(size_t)nj * 64 + lane] : 0.f;
  }
  __syncthreads();

  // GEMM1: u[p0..p0+31] per wave, lane=node
  int p0 = __builtin_amdgcn_readfirstlane(wv * 32);
  float u[32];
#pragma unroll
  for (int i = 0; i < 32; ++i) u[i] = 0.f;
  for (int kc = 0; kc < 64; kc += 4) {
    float4 av = *(const float4*)&pool[lane * 80 + kc];
    float a4[4] = {av.x, av.y, av.z, av.w};
#pragma unroll
    for (int q = 0; q < 4; ++q) {
      const float* wrow = w1t + (kc + q) * 256 + p0;
#pragma unroll
      for (int i = 0; i < 32; ++i) u[i] = fmaf(a4[q], wrow[i], u[i]);
    }
  }
  // bias + SiLU
#pragma unroll
  for (int i = 0; i < 32; ++i) {
    float v = u[i] + b1[p0 + i];
    u[i] = v / (1.f + __expf(-v));
  }
  // LN(256): local sums -> cross-wave reduce
  float s1 = 0.f, s2 = 0.f;
#pragma unroll
  for (int i = 0; i < 32; ++i) { s1 += u[i]; s2 = fmaf(u[i], u[i], s2); }
  ln1[wv * 64 + lane] = s1;
  ln2[wv * 64 + lane] = s2;
  __syncthreads();
  float t1 = 0.f, t2 = 0.f;
#pragma unroll
  for (int w = 0; w < 8; ++w) { t1 += ln1[w * 64 + lane]; t2 += ln2[w * 64 + lane]; }
  float mean = t1 * 0.00390625f;
  float var = t2 * 0.00390625f - mean * mean;
  float rs = rsqrtf(var + 1e-5f);
#pragma unroll
  for (int i = 0; i < 32; ++i) u[i] = (u[i] - mean) * rs * lng[p0 + i] + lnb[p0 + i];
  // write normalized u to LDS (overwrites h region; safe after ln sync)
#pragma unroll
  for (int q = 0; q < 8; ++q) {
    float4 w = {u[4 * q], u[4 * q + 1], u[4 * q + 2], u[4 * q + 3]};
    *(float4*)&pool[lane * 272 + p0 + 4 * q] = w;
  }
  __syncthreads();

  // GEMM2: o[f0..f0+7] per wave, lane=node
  int f0 = __builtin_amdgcn_readfirstlane(wv * 8);
  float o[8];
#pragma unroll
  for (int i = 0; i < 8; ++i) o[i] = 0.f;
  for (int kc = 0; kc < 256; kc += 4) {
    float4 av = *(const float4*)&pool[lane * 272 + kc];
    float a4[4] = {av.x, av.y, av.z, av.w};
#pragma unroll
    for (int q = 0; q < 4; ++q) {
      const float* wrow = w2t + (kc + q) * 64 + f0;
#pragma unroll
      for (int i = 0; i < 8; ++i) o[i] = fmaf(a4[q], wrow[i], o[i]);
    }
  }
#pragma unroll
  for (int i = 0; i < 8; ++i) o[i] += b2[f0 + i];
  __syncthreads();  // all GEMM2 reads of pool done
  // transpose via pool rows stride 80, then coalesced store
#pragma unroll
  for (int q = 0; q < 2; ++q) {
    float4 w = {o[4 * q], o[4 * q + 1], o[4 * q + 2], o[4 * q + 3]};
    *(float4*)&pool[lane * 80 + f0 + 4 * q] = w;
  }
  __syncthreads();
#pragma unroll
  for (int r = 0; r < 8; ++r) {
    int n = r * 8 + wv;
    int nj = base + n;
    if (nj < nN) out[(size_t)nj * 64 + lane] = pool[n * 80 + lane];
  }
}

extern "C" void kernel_launch(void* const* d_in, const int* in_sizes, int n_in,
                              void* d_out, int out_size, void* d_ws, size_t ws_size,
                              hipStream_t stream) {
  const float* x = (const float*)d_in[0];
  const void* edges = d_in[1];
  const float* conv_wl = (const float*)d_in[2];
  const float* conv_bl = (const float*)d_in[3];
  const float* conv_wr = (const float*)d_in[4];
  const float* ln_g = (const float*)d_in[5];
  const float* ln_b = (const float*)d_in[6];
  const float* adapter_w = (const float*)d_in[7];
  const float* adapter_b = (const float*)d_in[8];
  const float* mlp_w1 = (const float*)d_in[9];
  const float* mlp_b1 = (const float*)d_in[10];
  const float* mlp_lng = (const float*)d_in[11];
  const float* mlp_lnb = (const float*)d_in[12];
  const float* mlp_w2 = (const float*)d_in[13];
  const float* mlp_b2 = (const float*)d_in[14];

  const int N = in_sizes[0] / 64;
  const int E = in_sizes[1] / 2;
  const int NL = in_sizes[2] / (64 * 128);  // 5

  const int Na = (N + 63) & ~63;
  const int Ea = (E + 63) & ~63;
  int* deg = (int*)d_ws;
  int* cursor = deg + Na;
  int* row_start = cursor + Na;
  int* csr_src = row_start + (Na + 64);
  int* flag = csr_src + Ea;
  float* wt_all = (float*)(flag + 64);
  float* awt = wt_all + (size_t)NL * 192 * 64;
  float* w1t = awt + 64 * 64;
  float* w2t = w1t + 64 * 256;
  float* h_ws = w2t + 256 * 64;
  float* outf = (float*)d_out;

  hipMemsetAsync(deg, 0, (size_t)N * 4, stream);
  hipMemsetAsync(cursor, 0, (size_t)N * 4, stream);

  detect_idx64<<<1, 64, 0, stream>>>((const unsigned*)edges, flag);
  count_deg<<<1024, 256, 0, stream>>>(edges, flag, deg, E);
  scan_deg<<<1, 1024, 0, stream>>>(deg, row_start, N);
  fill_csr<<<1024, 256, 0, stream>>>(edges, flag, row_start, cursor, csr_src, E);

  int prep_tot = NL * 192 * 64 + 64 * 64 + 64 * 256 + 256 * 64;
  prep_weights<<<(prep_tot + 255) / 256, 256, 0, stream>>>(
      conv_wl, conv_wr, adapter_w, mlp_w1, mlp_w2, wt_all, awt, w1t, w2t, NL);

  const int nb = (N + 63) / 64;
  const float* src = x;
  for (int i = 0; i < NL; ++i) {
    float* dst = (((NL - i) & 1) == 1) ? h_ws : outf;
    const float* wt = wt_all + (size_t)i * 192 * 64;
    const float* bl = conv_bl + (size_t)i * 64;
    const float* g = ln_g + (size_t)i * 64;
    const float* b = ln_b + (size_t)i * 64;
    if (i == 0) {
      sage_layer<true><<<nb, 256, 0, stream>>>(src, dst, row_start, csr_src, wt, awt,
                                               bl, adapter_b, g, b, N);
    } else {
      sage_layer<false><<<nb, 256, 0, stream>>>(src, dst, row_start, csr_src, wt, awt,
                                                bl, adapter_b, g, b, N);
    }
    src = dst;
  }
  mlp_head<<<nb, 512, 0, stream>>>(src, outf, w1t, mlp_b1, mlp_lng, mlp_lnb, w2t, mlp_b2, N);
}

// Round 3
// 931.759 us; speedup vs baseline: 1.7603x; 1.7603x over previous
//
#include <hip/hip_runtime.h>

// SAGEEncoder v3: deep-MLP gather (preloaded indices in VGPRs, 16 loads in
// flight per batch), coalesced 3-phase scan, lane=node GEMM with scalar
// weights. fp32 throughout.

#define INFF 3.402823466e38f

__device__ __forceinline__ int rl_i(int v, int l) {
  return __builtin_amdgcn_readlane(v, l);
}

// ---- edge dtype detection: int64 iff the first 32 odd u32 slots are all zero ----
__global__ void detect_idx64(const unsigned* __restrict__ e, int* __restrict__ flag) {
  if (threadIdx.x == 0 && blockIdx.x == 0) {
    int is64 = 1;
    for (int i = 0; i < 32; ++i)
      if (e[2 * i + 1] != 0u) { is64 = 0; break; }
    *flag = is64;
  }
}

__device__ __forceinline__ int edge_val(const void* e, int is64, long long idx) {
  if (is64) return (int)((const long long*)e)[idx];
  return ((const int*)e)[idx];
}

__global__ void count_deg(const void* __restrict__ edges, const int* __restrict__ flag,
                          int* __restrict__ deg, int nE) {
  int is64 = *flag;
  long long E = nE;
  for (int i = blockIdx.x * blockDim.x + threadIdx.x; i < nE; i += gridDim.x * blockDim.x) {
    int dst = edge_val(edges, is64, E + i);
    atomicAdd(&deg[dst], 1);
  }
}

// ---- coalesced 3-phase exclusive scan ----
__global__ void deg_block_sum(const int* __restrict__ deg, int* __restrict__ bsum, int n) {
  __shared__ int w[4];
  int i = blockIdx.x * 256 + threadIdx.x;
  int v = (i < n) ? deg[i] : 0;
#pragma unroll
  for (int off = 32; off >= 1; off >>= 1) v += __shfl_down(v, off);
  if ((threadIdx.x & 63) == 0) w[threadIdx.x >> 6] = v;
  __syncthreads();
  if (threadIdx.x == 0) bsum[blockIdx.x] = w[0] + w[1] + w[2] + w[3];
}

__global__ void scan_bsum(int* __restrict__ bsum, int nb) {
  __shared__ int s[1024];
  int t = threadIdx.x;
  int v = (t < nb) ? bsum[t] : 0;
  s[t] = v;
  __syncthreads();
  for (int off = 1; off < 1024; off <<= 1) {
    int u = (t >= off) ? s[t - off] : 0;
    __syncthreads();
    s[t] += u;
    __syncthreads();
  }
  if (t < nb) bsum[t] = s[t] - v;  // exclusive
}

__global__ void scan_final(const int* __restrict__ deg, const int* __restrict__ bsum,
                           int* __restrict__ row_start, int n, int nE) {
  __shared__ int s[256];
  int t = threadIdx.x;
  int i = blockIdx.x * 256 + t;
  int v = (i < n) ? deg[i] : 0;
  s[t] = v;
  __syncthreads();
  int acc = v;
  for (int off = 1; off < 256; off <<= 1) {
    int u = (t >= off) ? s[t - off] : 0;
    __syncthreads();
    acc += u;
    s[t] = acc;
    __syncthreads();
  }
  if (i < n) row_start[i] = acc - v + bsum[blockIdx.x];
  if (i == n) row_start[n] = nE;
}

__global__ void fill_csr(const void* __restrict__ edges, const int* __restrict__ flag,
                         const int* __restrict__ row_start, int* __restrict__ cursor,
                         int* __restrict__ csr_src, int nE) {
  int is64 = *flag;
  long long E = nE;
  for (int i = blockIdx.x * blockDim.x + threadIdx.x; i < nE; i += gridDim.x * blockDim.x) {
    int src = edge_val(edges, is64, i);
    int dst = edge_val(edges, is64, E + i);
    int p = atomicAdd(&cursor[dst], 1);
    csr_src[row_start[dst] + p] = src;
  }
}

// ---- precompute transposed weights ----
__global__ void prep_weights(const float* __restrict__ wl, const float* __restrict__ wr,
                             const float* __restrict__ aw, const float* __restrict__ w1,
                             const float* __restrict__ w2,
                             float* __restrict__ wt, float* __restrict__ awt,
                             float* __restrict__ w1t, float* __restrict__ w2t, int nl) {
  int i = blockIdx.x * 256 + threadIdx.x;
  int tot_wt = nl * 192 * 64;
  if (i < tot_wt) {
    int l = i / (192 * 64);
    int r = i % (192 * 64);
    int k = r >> 6, f = r & 63;
    wt[i] = (k < 128) ? wl[(size_t)l * 64 * 128 + f * 128 + k]
                      : wr[(size_t)l * 64 * 64 + f * 64 + (k - 128)];
  } else {
    int j = i - tot_wt;
    if (j < 64 * 64) {
      int k = j >> 6, f = j & 63;
      awt[j] = aw[f * 64 + k];
    } else if (j < 64 * 64 + 64 * 256) {
      int q = j - 64 * 64;
      int k = q >> 8, p = q & 255;
      w1t[q] = w1[p * 64 + k];
    } else if (j < 64 * 64 + 64 * 256 + 256 * 64) {
      int q = j - 64 * 64 - 64 * 256;
      int k = q >> 6, f = q & 63;
      w2t[q] = w2[f * 256 + k];
    }
  }
}

// ---- fused SAGE layer ----
// Block: 256 threads (4 waves), 64 nodes. Phase1 lane=feature; Phase2 lane=node.
template <bool FIRST>
__global__ __launch_bounds__(256) void sage_layer(
    const float* __restrict__ in, float* __restrict__ out,
    const int* __restrict__ row_start, const int* __restrict__ csr_src,
    const float* __restrict__ wt,    // [192][64]
    const float* __restrict__ awt,   // [64][64]
    const float* __restrict__ bl, const float* __restrict__ ab,
    const float* __restrict__ lng, const float* __restrict__ lnb,
    int nN) {
  __shared__ float lds[64 * 200 + 512];  // agg[64][200], ln1[256], ln2[256]
  float* agg = lds;
  float* ln1 = lds + 12800;
  float* ln2 = ln1 + 256;

  int t = threadIdx.x;
  int wv = __builtin_amdgcn_readfirstlane(t >> 6);  // force wave-uniform SGPR
  int lane = t & 63;
  int base = blockIdx.x * 64;
  int wn0 = base + wv * 16;

  // ---- Phase 1a: uniform row bounds (SGPR) + index preload (VGPR) + x rows ----
  int rs[17];
#pragma unroll
  for (int i = 0; i <= 16; ++i) rs[i] = row_start[min(wn0 + i, nN)];

  int ivA[4], ivB[4];
#pragma unroll
  for (int g = 0; g < 4; ++g) {
    int Eg = rs[4 * g];
    int lenm1 = max(rs[4 * g + 4] - Eg - 1, 0);
    ivA[g] = csr_src[Eg + min(lane, lenm1)];
    ivB[g] = csr_src[Eg + min(lane + 64, lenm1)];
  }

#pragma unroll
  for (int r = 0; r < 16; ++r) {
    int nj = wn0 + r;
    float xv = (nj < nN) ? in[(size_t)nj * 64 + lane] : 0.f;
    agg[(wv * 16 + r) * 200 + 128 + lane] = xv;
  }

  // ---- Phase 1b: aggregation, 4 nodes lockstep, 16 gathers per batch ----
#pragma unroll
  for (int g = 0; g < 4; ++g) {
    int e0g = rs[4 * g];
    int off[4], dg[4], dgm[4];
#pragma unroll
    for (int j = 0; j < 4; ++j) {
      off[j] = rs[4 * g + j] - e0g;
      dg[j] = rs[4 * g + j + 1] - rs[4 * g + j];
      dgm[j] = max(dg[j] - 1, 0);
    }
    int mm = max(max(dg[0], dg[1]), max(dg[2], dg[3]));
    int len = rs[4 * g + 4] - e0g;
    float mx[4], sm[4];
#pragma unroll
    for (int j = 0; j < 4; ++j) { mx[j] = -INFF; sm[j] = 0.f; }

    if (len <= 128) {  // fast path: indices already in registers
      for (int tt = 0; tt < mm; tt += 4) {
        float v[16];
#pragma unroll
        for (int u = 0; u < 4; ++u) {
#pragma unroll
          for (int j = 0; j < 4; ++j) {
            int p = off[j] + min(tt + u, dgm[j]);  // uniform
            int s_ = (p < 64) ? rl_i(ivA[g], p) : rl_i(ivB[g], p - 64);
            s_ = min((unsigned)s_, (unsigned)(nN - 1));
            v[u * 4 + j] = in[(size_t)s_ * 64 + lane];
          }
        }
#pragma unroll
        for (int u = 0; u < 4; ++u) {
#pragma unroll
          for (int j = 0; j < 4; ++j) {
            float vv = v[u * 4 + j];
            mx[j] = fmaxf(mx[j], vv);              // clamp makes extras idempotent
            sm[j] += (tt + u < dg[j]) ? vv : 0.f;  // sum needs the mask
          }
        }
      }
    } else {  // slow fallback (degree sum > 128 in a 4-node group): direct loads
      for (int tt = 0; tt < mm; ++tt) {
#pragma unroll
        for (int j = 0; j < 4; ++j) {
          int act = tt < dg[j];
          int s_ = csr_src[e0g + off[j] + min(tt, dgm[j])];
          s_ = min((unsigned)s_, (unsigned)(nN - 1));
          float vv = in[(size_t)s_ * 64 + lane];
          mx[j] = fmaxf(mx[j], vv);
          sm[j] += act ? vv : 0.f;
        }
      }
    }

#pragma unroll
    for (int j = 0; j < 4; ++j) {
      int nl_ = wv * 16 + g * 4 + j;
      agg[nl_ * 200 + lane] = (dg[j] > 0) ? mx[j] : 0.f;
      agg[nl_ * 200 + 64 + lane] = sm[j] / fmaxf((float)dg[j], 1.f);
    }
  }
  __syncthreads();

  // ---- Phase 2: GEMM. lane = node, wave owns features f0..f0+15. ----
  int f0 = __builtin_amdgcn_readfirstlane(wv * 16);
  float acc[16], accr[16];
#pragma unroll
  for (int i = 0; i < 16; ++i) { acc[i] = 0.f; accr[i] = 0.f; }
  for (int kc = 0; kc < 192; kc += 4) {
    float4 av = *(const float4*)&agg[lane * 200 + kc];
    float a4[4] = {av.x, av.y, av.z, av.w};
#pragma unroll
    for (int q = 0; q < 4; ++q) {
      int k = kc + q;
      const float* wrow = wt + k * 64 + f0;
#pragma unroll
      for (int i = 0; i < 16; ++i) acc[i] = fmaf(a4[q], wrow[i], acc[i]);
      if (FIRST) {
        if (k >= 128) {
          const float* arow = awt + (k - 128) * 64 + f0;
#pragma unroll
          for (int i = 0; i < 16; ++i) accr[i] = fmaf(a4[q], arow[i], accr[i]);
        }
      }
    }
  }

  // ---- Phase 3: bias, LN, residual, SiLU, store ----
#pragma unroll
  for (int i = 0; i < 16; ++i) acc[i] += bl[f0 + i];
  float s1 = 0.f, s2 = 0.f;
#pragma unroll
  for (int i = 0; i < 16; ++i) { s1 += acc[i]; s2 = fmaf(acc[i], acc[i], s2); }
  ln1[wv * 64 + lane] = s1;
  ln2[wv * 64 + lane] = s2;
  __syncthreads();
  float t1 = (ln1[lane] + ln1[64 + lane]) + (ln1[128 + lane] + ln1[192 + lane]);
  float t2 = (ln2[lane] + ln2[64 + lane]) + (ln2[128 + lane] + ln2[192 + lane]);
  float mean = t1 * 0.015625f;
  float var = t2 * 0.015625f - mean * mean;
  float rs_ = rsqrtf(var + 1e-5f);

  float res[16];
  if (FIRST) {
#pragma unroll
    for (int i = 0; i < 16; ++i) res[i] = accr[i] + ab[f0 + i];
  } else {
#pragma unroll
    for (int q = 0; q < 4; ++q) {
      float4 rv = *(const float4*)&agg[lane * 200 + 128 + f0 + 4 * q];
      res[4 * q + 0] = rv.x; res[4 * q + 1] = rv.y; res[4 * q + 2] = rv.z; res[4 * q + 3] = rv.w;
    }
  }
  float y[16];
#pragma unroll
  for (int i = 0; i < 16; ++i) {
    float v = (acc[i] - mean) * rs_ * lng[f0 + i] + lnb[f0 + i] + res[i];
    y[i] = v / (1.f + __expf(-v));
  }
#pragma unroll
  for (int q = 0; q < 4; ++q) {
    float4 w = {y[4 * q], y[4 * q + 1], y[4 * q + 2], y[4 * q + 3]};
    *(float4*)&agg[lane * 200 + f0 + 4 * q] = w;
  }
  __syncthreads();
#pragma unroll
  for (int r = 0; r < 16; ++r) {
    int nl_ = r * 4 + wv;
    int nj = base + nl_;
    if (nj < nN) out[(size_t)nj * 64 + lane] = agg[nl_ * 200 + lane];
  }
}

// ---- MLP head ----
__global__ __launch_bounds__(512) void mlp_head(
    const float* __restrict__ in, float* __restrict__ out,
    const float* __restrict__ w1t, const float* __restrict__ b1,
    const float* __restrict__ lng, const float* __restrict__ lnb,
    const float* __restrict__ w2t, const float* __restrict__ b2, int nN) {
  __shared__ float pool[64 * 272 + 1024];
  float* ln1 = pool + 17408;
  float* ln2 = ln1 + 512;

  int t = threadIdx.x;
  int wv = __builtin_amdgcn_readfirstlane(t >> 6);
  int lane = t & 63;
  int base = blockIdx.x * 64;

#pragma unroll
  for (int r = 0; r < 8; ++r) {
    int n = r * 8 + wv;
    int nj = base + n;
    pool[n * 80 + lane] = (nj < nN) ? in[(size_t)nj * 64 + lane] : 0.f;
  }
  __syncthreads();

  int p0 = __builtin_amdgcn_readfirstlane(wv * 32);
  float u[32];
#pragma unroll
  for (int i = 0; i < 32; ++i) u[i] = 0.f;
  for (int kc = 0; kc < 64; kc += 4) {
    float4 av = *(const float4*)&pool[lane * 80 + kc];
    float a4[4] = {av.x, av.y, av.z, av.w};
#pragma unroll
    for (int q = 0; q < 4; ++q) {
      const float* wrow = w1t + (kc + q) * 256 + p0;
#pragma unroll
      for (int i = 0; i < 32; ++i) u[i] = fmaf(a4[q], wrow[i], u[i]);
    }
  }
#pragma unroll
  for (int i = 0; i < 32; ++i) {
    float v = u[i] + b1[p0 + i];
    u[i] = v / (1.f + __expf(-v));
  }
  float s1 = 0.f, s2 = 0.f;
#pragma unroll
  for (int i = 0; i < 32; ++i) { s1 += u[i]; s2 = fmaf(u[i], u[i], s2); }
  ln1[wv * 64 + lane] = s1;
  ln2[wv * 64 + lane] = s2;
  __syncthreads();
  float t1 = 0.f, t2 = 0.f;
#pragma unroll
  for (int w = 0; w < 8; ++w) { t1 += ln1[w * 64 + lane]; t2 += ln2[w * 64 + lane]; }
  float mean = t1 * 0.00390625f;
  float var = t2 * 0.00390625f - mean * mean;
  float rs_ = rsqrtf(var + 1e-5f);
#pragma unroll
  for (int i = 0; i < 32; ++i) u[i] = (u[i] - mean) * rs_ * lng[p0 + i] + lnb[p0 + i];
#pragma unroll
  for (int q = 0; q < 8; ++q) {
    float4 w = {u[4 * q], u[4 * q + 1], u[4 * q + 2], u[4 * q + 3]};
    *(float4*)&pool[lane * 272 + p0 + 4 * q] = w;
  }
  __syncthreads();

  int f0 = __builtin_amdgcn_readfirstlane(wv * 8);
  float o[8];
#pragma unroll
  for (int i = 0; i < 8; ++i) o[i] = 0.f;
  for (int kc = 0; kc < 256; kc += 4) {
    float4 av = *(const float4*)&pool[lane * 272 + kc];
    float a4[4] = {av.x, av.y, av.z, av.w};
#pragma unroll
    for (int q = 0; q < 4; ++q) {
      const float* wrow = w2t + (kc + q) * 64 + f0;
#pragma unroll
      for (int i = 0; i < 8; ++i) o[i] = fmaf(a4[q], wrow[i], o[i]);
    }
  }
#pragma unroll
  for (int i = 0; i < 8; ++i) o[i] += b2[f0 + i];
  __syncthreads();
#pragma unroll
  for (int q = 0; q < 2; ++q) {
    float4 w = {o[4 * q], o[4 * q + 1], o[4 * q + 2], o[4 * q + 3]};
    *(float4*)&pool[lane * 80 + f0 + 4 * q] = w;
  }
  __syncthreads();
#pragma unroll
  for (int r = 0; r < 8; ++r) {
    int n = r * 8 + wv;
    int nj = base + n;
    if (nj < nN) out[(size_t)nj * 64 + lane] = pool[n * 80 + lane];
  }
}

extern "C" void kernel_launch(void* const* d_in, const int* in_sizes, int n_in,
                              void* d_out, int out_size, void* d_ws, size_t ws_size,
                              hipStream_t stream) {
  const float* x = (const float*)d_in[0];
  const void* edges = d_in[1];
  const float* conv_wl = (const float*)d_in[2];
  const float* conv_bl = (const float*)d_in[3];
  const float* conv_wr = (const float*)d_in[4];
  const float* ln_g = (const float*)d_in[5];
  const float* ln_b = (const float*)d_in[6];
  const float* adapter_w = (const float*)d_in[7];
  const float* adapter_b = (const float*)d_in[8];
  const float* mlp_w1 = (const float*)d_in[9];
  const float* mlp_b1 = (const float*)d_in[10];
  const float* mlp_lng = (const float*)d_in[11];
  const float* mlp_lnb = (const float*)d_in[12];
  const float* mlp_w2 = (const float*)d_in[13];
  const float* mlp_b2 = (const float*)d_in[14];

  const int N = in_sizes[0] / 64;
  const int E = in_sizes[1] / 2;
  const int NL = in_sizes[2] / (64 * 128);  // 5

  const int Na = (N + 63) & ~63;
  const int Ea = (E + 63) & ~63;
  int* deg = (int*)d_ws;
  int* cursor = deg + Na;
  int* row_start = cursor + Na;
  int* csr_src = row_start + (Na + 64);
  int* flag = csr_src + (Ea + 256);  // pad beyond E for clamped preloads
  int* bsum = flag + 64;
  float* wt_all = (float*)(bsum + 1024);
  float* awt = wt_all + (size_t)NL * 192 * 64;
  float* w1t = awt + 64 * 64;
  float* w2t = w1t + 64 * 256;
  float* h_ws = w2t + 256 * 64;
  float* outf = (float*)d_out;

  hipMemsetAsync(deg, 0, (size_t)N * 4, stream);
  hipMemsetAsync(cursor, 0, (size_t)N * 4, stream);

  detect_idx64<<<1, 64, 0, stream>>>((const unsigned*)edges, flag);
  count_deg<<<1024, 256, 0, stream>>>(edges, flag, deg, E);

  const int nsb = (N + 255) / 256;  // scan blocks (391)
  deg_block_sum<<<nsb, 256, 0, stream>>>(deg, bsum, N);
  scan_bsum<<<1, 1024, 0, stream>>>(bsum, nsb);
  scan_final<<<nsb, 256, 0, stream>>>(deg, bsum, row_start, N, E);

  fill_csr<<<1024, 256, 0, stream>>>(edges, flag, row_start, cursor, csr_src, E);

  int prep_tot = NL * 192 * 64 + 64 * 64 + 64 * 256 + 256 * 64;
  prep_weights<<<(prep_tot + 255) / 256, 256, 0, stream>>>(
      conv_wl, conv_wr, adapter_w, mlp_w1, mlp_w2, wt_all, awt, w1t, w2t, NL);

  const int nb = (N + 63) / 64;
  const float* src = x;
  for (int i = 0; i < NL; ++i) {
    float* dst = (((NL - i) & 1) == 1) ? h_ws : outf;
    const float* wt = wt_all + (size_t)i * 192 * 64;
    const float* bl = conv_bl + (size_t)i * 64;
    const float* g = ln_g + (size_t)i * 64;
    const float* b = ln_b + (size_t)i * 64;
    if (i == 0) {
      sage_layer<true><<<nb, 256, 0, stream>>>(src, dst, row_start, csr_src, wt, awt,
                                               bl, adapter_b, g, b, N);
    } else {
      sage_layer<false><<<nb, 256, 0, stream>>>(src, dst, row_start, csr_src, wt, awt,
                                                bl, adapter_b, g, b, N);
    }
    src = dst;
  }
  mlp_head<<<nb, 512, 0, stream>>>(src, outf, w1t, mlp_b1, mlp_lng, mlp_lnb, w2t, mlp_b2, N);
}

// Round 4
// 928.726 us; speedup vs baseline: 1.7661x; 1.0033x over previous
//
#include <hip/hip_runtime.h>

// SAGEEncoder v4: float4 gather (4 edges per wave-load, idx via LDS),
// odd-quad LDS strides (conflict-free b128), 32-bit gather addressing.

#define INFF 3.402823466e38f

// ---- edge dtype detection: int64 iff the first 32 odd u32 slots are all zero ----
__global__ void detect_idx64(const unsigned* __restrict__ e, int* __restrict__ flag) {
  if (threadIdx.x == 0 && blockIdx.x == 0) {
    int is64 = 1;
    for (int i = 0; i < 32; ++i)
      if (e[2 * i + 1] != 0u) { is64 = 0; break; }
    *flag = is64;
  }
}

__device__ __forceinline__ int edge_val(const void* e, int is64, long long idx) {
  if (is64) return (int)((const long long*)e)[idx];
  return ((const int*)e)[idx];
}

__global__ void count_deg(const void* __restrict__ edges, const int* __restrict__ flag,
                          int* __restrict__ deg, int nE) {
  int is64 = *flag;
  long long E = nE;
  for (int i = blockIdx.x * blockDim.x + threadIdx.x; i < nE; i += gridDim.x * blockDim.x) {
    int dst = edge_val(edges, is64, E + i);
    atomicAdd(&deg[dst], 1);
  }
}

// ---- coalesced 3-phase exclusive scan ----
__global__ void deg_block_sum(const int* __restrict__ deg, int* __restrict__ bsum, int n) {
  __shared__ int w[4];
  int i = blockIdx.x * 256 + threadIdx.x;
  int v = (i < n) ? deg[i] : 0;
#pragma unroll
  for (int off = 32; off >= 1; off >>= 1) v += __shfl_down(v, off);
  if ((threadIdx.x & 63) == 0) w[threadIdx.x >> 6] = v;
  __syncthreads();
  if (threadIdx.x == 0) bsum[blockIdx.x] = w[0] + w[1] + w[2] + w[3];
}

__global__ void scan_bsum(int* __restrict__ bsum, int nb) {
  __shared__ int s[1024];
  int t = threadIdx.x;
  int v = (t < nb) ? bsum[t] : 0;
  s[t] = v;
  __syncthreads();
  for (int off = 1; off < 1024; off <<= 1) {
    int u = (t >= off) ? s[t - off] : 0;
    __syncthreads();
    s[t] += u;
    __syncthreads();
  }
  if (t < nb) bsum[t] = s[t] - v;  // exclusive
}

__global__ void scan_final(const int* __restrict__ deg, const int* __restrict__ bsum,
                           int* __restrict__ row_start, int n, int nE) {
  __shared__ int s[256];
  int t = threadIdx.x;
  int i = blockIdx.x * 256 + t;
  int v = (i < n) ? deg[i] : 0;
  s[t] = v;
  __syncthreads();
  int acc = v;
  for (int off = 1; off < 256; off <<= 1) {
    int u = (t >= off) ? s[t - off] : 0;
    __syncthreads();
    acc += u;
    s[t] = acc;
    __syncthreads();
  }
  if (i < n) row_start[i] = acc - v + bsum[blockIdx.x];
  if (i == n) row_start[n] = nE;
}

__global__ void fill_csr(const void* __restrict__ edges, const int* __restrict__ flag,
                         const int* __restrict__ row_start, int* __restrict__ cursor,
                         int* __restrict__ csr_src, int nE) {
  int is64 = *flag;
  long long E = nE;
  for (int i = blockIdx.x * blockDim.x + threadIdx.x; i < nE; i += gridDim.x * blockDim.x) {
    int src = edge_val(edges, is64, i);
    int dst = edge_val(edges, is64, E + i);
    int p = atomicAdd(&cursor[dst], 1);
    csr_src[row_start[dst] + p] = src;
  }
}

// ---- precompute transposed weights ----
__global__ void prep_weights(const float* __restrict__ wl, const float* __restrict__ wr,
                             const float* __restrict__ aw, const float* __restrict__ w1,
                             const float* __restrict__ w2,
                             float* __restrict__ wt, float* __restrict__ awt,
                             float* __restrict__ w1t, float* __restrict__ w2t, int nl) {
  int i = blockIdx.x * 256 + threadIdx.x;
  int tot_wt = nl * 192 * 64;
  if (i < tot_wt) {
    int l = i / (192 * 64);
    int r = i % (192 * 64);
    int k = r >> 6, f = r & 63;
    wt[i] = (k < 128) ? wl[(size_t)l * 64 * 128 + f * 128 + k]
                      : wr[(size_t)l * 64 * 64 + f * 64 + (k - 128)];
  } else {
    int j = i - tot_wt;
    if (j < 64 * 64) {
      int k = j >> 6, f = j & 63;
      awt[j] = aw[f * 64 + k];
    } else if (j < 64 * 64 + 64 * 256) {
      int q = j - 64 * 64;
      int k = q >> 8, p = q & 255;
      w1t[q] = w1[p * 64 + k];
    } else if (j < 64 * 64 + 64 * 256 + 256 * 64) {
      int q = j - 64 * 64 - 64 * 256;
      int k = q >> 6, f = q & 63;
      w2t[q] = w2[f * 256 + k];
    }
  }
}

// ---- fused SAGE layer ----
// Block: 256 threads (4 waves), 64 nodes.
// Phase1 gather: 16-lane groups, 4 edges per float4 wave-load, idx from LDS.
// Phase2 GEMM: lane=node, stride-196 agg (odd quad -> conflict-free b128).
#define AS 196  // agg row stride in floats (49 quads, odd)
template <bool FIRST>
__global__ __launch_bounds__(256, 2) void sage_layer(
    const float* __restrict__ in, float* __restrict__ out,
    const int* __restrict__ row_start, const int* __restrict__ csr_src,
    const float* __restrict__ wt,    // [192][64]
    const float* __restrict__ awt,   // [64][64]
    const float* __restrict__ bl, const float* __restrict__ ab,
    const float* __restrict__ lng, const float* __restrict__ lnb,
    int nN) {
  __shared__ float lds[12544 + 2080 + 512];  // agg[64][196] | idx[4][520] | ln1/ln2
  float* agg = lds;
  int* idxs = (int*)(lds + 12544);
  float* ln1 = lds + 12544 + 2080;
  float* ln2 = ln1 + 256;

  int t = threadIdx.x;
  int wv = __builtin_amdgcn_readfirstlane(t >> 6);
  int lane = t & 63;
  int g_lane = lane >> 4;         // edge-slot group 0..3
  int fq4 = (lane & 15) * 4;      // feature quad base
  int base = blockIdx.x * 64;
  int wn0 = base + wv * 16;

  // ---- uniform row bounds (SGPR) ----
  int rs[17];
#pragma unroll
  for (int i = 0; i <= 16; ++i) rs[i] = row_start[min(wn0 + i, nN)];

  // ---- per-lane node bounds for the 4 outer groups ----
  int offL[4], dgL[4], dgmL[4];
#pragma unroll
  for (int G = 0; G < 4; ++G) {
    int nj = wn0 + G * 4 + g_lane;
    int a = row_start[min(nj, nN)];
    int b = row_start[min(nj + 1, nN)];
    offL[G] = a - rs[4 * G];
    dgL[G] = b - a;
    dgmL[G] = max(dgL[G] - 1, 0);
  }

  // ---- stage neighbor indices into LDS (<=128 per 4-node group) ----
#pragma unroll
  for (int G = 0; G < 4; ++G) {
    int Eg = rs[4 * G];
    int len = rs[4 * G + 4] - Eg;
    if (len <= 128) {
      int lenm1 = max(len - 1, 0);
      int s0 = csr_src[Eg + min(lane, lenm1)];
      int s1 = csr_src[Eg + min(lane + 64, lenm1)];
      idxs[wv * 520 + G * 130 + lane] = min((unsigned)s0, (unsigned)(nN - 1));
      idxs[wv * 520 + G * 130 + 64 + lane] = min((unsigned)s1, (unsigned)(nN - 1));
    }
  }

  // ---- stage x rows (float4, 4 nodes per load) ----
#pragma unroll
  for (int R = 0; R < 4; ++R) {
    int nloc = R * 4 + g_lane;
    int nj = wn0 + nloc;
    bool ok = nj < nN;
    unsigned njc = min((unsigned)nj, (unsigned)(nN - 1));
    float4 xv = *(const float4*)(in + njc * 64u + fq4);
    if (!ok) xv = make_float4(0.f, 0.f, 0.f, 0.f);
    *(float4*)&agg[(wv * 16 + nloc) * AS + 128 + fq4] = xv;
  }

  // ---- gather: 4 nodes lockstep, 4 edges per wave-load, unroll 8 ----
#pragma unroll
  for (int G = 0; G < 4; ++G) {
    int Eg = rs[4 * G];
    int len = rs[4 * G + 4] - Eg;
    int d0 = rs[4 * G + 1] - rs[4 * G + 0], d1 = rs[4 * G + 2] - rs[4 * G + 1];
    int d2 = rs[4 * G + 3] - rs[4 * G + 2], d3 = rs[4 * G + 4] - rs[4 * G + 3];
    int mm = max(max(d0, d1), max(d2, d3));
    int offl = offL[G], dgl = dgL[G], dgml = dgmL[G];
    int ibase = wv * 520 + G * 130;
    float4 mx = make_float4(-INFF, -INFF, -INFF, -INFF);
    float4 sm = make_float4(0.f, 0.f, 0.f, 0.f);

    if (len <= 128) {
      for (int tt = 0; tt < mm; tt += 8) {
        float4 v[8];
#pragma unroll
        for (int u = 0; u < 8; ++u) {
          int p = offl + min(tt + u, dgml);
          unsigned si = (unsigned)idxs[ibase + p];
          v[u] = *(const float4*)(in + si * 64u + fq4);
        }
#pragma unroll
        for (int u = 0; u < 8; ++u) {
          float m = (tt + u < dgl) ? 1.f : 0.f;
          mx.x = fmaxf(mx.x, v[u].x); mx.y = fmaxf(mx.y, v[u].y);
          mx.z = fmaxf(mx.z, v[u].z); mx.w = fmaxf(mx.w, v[u].w);
          sm.x = fmaf(v[u].x, m, sm.x); sm.y = fmaf(v[u].y, m, sm.y);
          sm.z = fmaf(v[u].z, m, sm.z); sm.w = fmaf(v[u].w, m, sm.w);
        }
      }
    } else {  // rare: >128 edges in a 4-node group
      for (int tt = 0; tt < mm; tt += 2) {
        float4 v[2];
#pragma unroll
        for (int u = 0; u < 2; ++u) {
          int p = offl + min(tt + u, dgml);
          unsigned si = min((unsigned)csr_src[Eg + p], (unsigned)(nN - 1));
          v[u] = *(const float4*)(in + si * 64u + fq4);
        }
#pragma unroll
        for (int u = 0; u < 2; ++u) {
          float m = (tt + u < dgl) ? 1.f : 0.f;
          mx.x = fmaxf(mx.x, v[u].x); mx.y = fmaxf(mx.y, v[u].y);
          mx.z = fmaxf(mx.z, v[u].z); mx.w = fmaxf(mx.w, v[u].w);
          sm.x = fmaf(v[u].x, m, sm.x); sm.y = fmaf(v[u].y, m, sm.y);
          sm.z = fmaf(v[u].z, m, sm.z); sm.w = fmaf(v[u].w, m, sm.w);
        }
      }
    }

    int nloc = wv * 16 + G * 4 + g_lane;
    float4 ax;
    ax.x = (dgl > 0) ? mx.x : 0.f; ax.y = (dgl > 0) ? mx.y : 0.f;
    ax.z = (dgl > 0) ? mx.z : 0.f; ax.w = (dgl > 0) ? mx.w : 0.f;
    float r = 1.f / (float)max(dgl, 1);
    float4 am = make_float4(sm.x * r, sm.y * r, sm.z * r, sm.w * r);
    *(float4*)&agg[nloc * AS + fq4] = ax;
    *(float4*)&agg[nloc * AS + 64 + fq4] = am;
  }
  __syncthreads();

  // ---- Phase 2: GEMM. lane = node, wave owns features f0..f0+15. ----
  int f0 = __builtin_amdgcn_readfirstlane(wv * 16);
  float acc[16], accr[16];
#pragma unroll
  for (int i = 0; i < 16; ++i) { acc[i] = 0.f; accr[i] = 0.f; }
  for (int kc = 0; kc < 192; kc += 4) {
    float4 av = *(const float4*)&agg[lane * AS + kc];
    float a4[4] = {av.x, av.y, av.z, av.w};
#pragma unroll
    for (int q = 0; q < 4; ++q) {
      int k = kc + q;
      const float* wrow = wt + k * 64 + f0;
#pragma unroll
      for (int i = 0; i < 16; ++i) acc[i] = fmaf(a4[q], wrow[i], acc[i]);
      if (FIRST) {
        if (k >= 128) {
          const float* arow = awt + (k - 128) * 64 + f0;
#pragma unroll
          for (int i = 0; i < 16; ++i) accr[i] = fmaf(a4[q], arow[i], accr[i]);
        }
      }
    }
  }

  // ---- Phase 3: bias, LN, residual, SiLU, store ----
#pragma unroll
  for (int i = 0; i < 16; ++i) acc[i] += bl[f0 + i];
  float s1 = 0.f, s2 = 0.f;
#pragma unroll
  for (int i = 0; i < 16; ++i) { s1 += acc[i]; s2 = fmaf(acc[i], acc[i], s2); }
  ln1[wv * 64 + lane] = s1;
  ln2[wv * 64 + lane] = s2;
  __syncthreads();
  float t1 = (ln1[lane] + ln1[64 + lane]) + (ln1[128 + lane] + ln1[192 + lane]);
  float t2 = (ln2[lane] + ln2[64 + lane]) + (ln2[128 + lane] + ln2[192 + lane]);
  float mean = t1 * 0.015625f;
  float var = t2 * 0.015625f - mean * mean;
  float rs_ = rsqrtf(var + 1e-5f);

  float res[16];
  if (FIRST) {
#pragma unroll
    for (int i = 0; i < 16; ++i) res[i] = accr[i] + ab[f0 + i];
  } else {
#pragma unroll
    for (int q = 0; q < 4; ++q) {
      float4 rv = *(const float4*)&agg[lane * AS + 128 + f0 + 4 * q];
      res[4 * q + 0] = rv.x; res[4 * q + 1] = rv.y; res[4 * q + 2] = rv.z; res[4 * q + 3] = rv.w;
    }
  }
  float y[16];
#pragma unroll
  for (int i = 0; i < 16; ++i) {
    float v = (acc[i] - mean) * rs_ * lng[f0 + i] + lnb[f0 + i] + res[i];
    y[i] = v / (1.f + __expf(-v));
  }
#pragma unroll
  for (int q = 0; q < 4; ++q) {
    float4 w = {y[4 * q], y[4 * q + 1], y[4 * q + 2], y[4 * q + 3]};
    *(float4*)&agg[lane * AS + f0 + 4 * q] = w;
  }
  __syncthreads();
#pragma unroll
  for (int r = 0; r < 16; ++r) {
    int nl_ = r * 4 + wv;
    int nj = base + nl_;
    if (nj < nN) out[(size_t)nj * 64 + lane] = agg[nl_ * AS + lane];
  }
}

// ---- MLP head (strides 84/276: odd quads, conflict-free b128) ----
__global__ __launch_bounds__(512, 2) void mlp_head(
    const float* __restrict__ in, float* __restrict__ out,
    const float* __restrict__ w1t, const float* __restrict__ b1,
    const float* __restrict__ lng, const float* __restrict__ lnb,
    const float* __restrict__ w2t, const float* __restrict__ b2, int nN) {
  __shared__ float pool[64 * 276 + 1024];
  float* ln1 = pool + 64 * 276;
  float* ln2 = ln1 + 512;

  int t = threadIdx.x;
  int wv = __builtin_amdgcn_readfirstlane(t >> 6);
  int lane = t & 63;
  int base = blockIdx.x * 64;

#pragma unroll
  for (int r = 0; r < 8; ++r) {
    int n = r * 8 + wv;
    int nj = base + n;
    pool[n * 84 + lane] = (nj < nN) ? in[(size_t)nj * 64 + lane] : 0.f;
  }
  __syncthreads();

  int p0 = __builtin_amdgcn_readfirstlane(wv * 32);
  float u[32];
#pragma unroll
  for (int i = 0; i < 32; ++i) u[i] = 0.f;
  for (int kc = 0; kc < 64; kc += 4) {
    float4 av = *(const float4*)&pool[lane * 84 + kc];
    float a4[4] = {av.x, av.y, av.z, av.w};
#pragma unroll
    for (int q = 0; q < 4; ++q) {
      const float* wrow = w1t + (kc + q) * 256 + p0;
#pragma unroll
      for (int i = 0; i < 32; ++i) u[i] = fmaf(a4[q], wrow[i], u[i]);
    }
  }
#pragma unroll
  for (int i = 0; i < 32; ++i) {
    float v = u[i] + b1[p0 + i];
    u[i] = v / (1.f + __expf(-v));
  }
  float s1 = 0.f, s2 = 0.f;
#pragma unroll
  for (int i = 0; i < 32; ++i) { s1 += u[i]; s2 = fmaf(u[i], u[i], s2); }
  ln1[wv * 64 + lane] = s1;
  ln2[wv * 64 + lane] = s2;
  __syncthreads();
  float t1 = 0.f, t2 = 0.f;
#pragma unroll
  for (int w = 0; w < 8; ++w) { t1 += ln1[w * 64 + lane]; t2 += ln2[w * 64 + lane]; }
  float mean = t1 * 0.00390625f;
  float var = t2 * 0.00390625f - mean * mean;
  float rs_ = rsqrtf(var + 1e-5f);
#pragma unroll
  for (int i = 0; i < 32; ++i) u[i] = (u[i] - mean) * rs_ * lng[p0 + i] + lnb[p0 + i];
#pragma unroll
  for (int q = 0; q < 8; ++q) {
    float4 w = {u[4 * q], u[4 * q + 1], u[4 * q + 2], u[4 * q + 3]};
    *(float4*)&pool[lane * 276 + p0 + 4 * q] = w;
  }
  __syncthreads();

  int f0 = __builtin_amdgcn_readfirstlane(wv * 8);
  float o[8];
#pragma unroll
  for (int i = 0; i < 8; ++i) o[i] = 0.f;
  for (int kc = 0; kc < 256; kc += 4) {
    float4 av = *(const float4*)&pool[lane * 276 + kc];
    float a4[4] = {av.x, av.y, av.z, av.w};
#pragma unroll
    for (int q = 0; q < 4; ++q) {
      const float* wrow = w2t + (kc + q) * 64 + f0;
#pragma unroll
      for (int i = 0; i < 8; ++i) o[i] = fmaf(a4[q], wrow[i], o[i]);
    }
  }
#pragma unroll
  for (int i = 0; i < 8; ++i) o[i] += b2[f0 + i];
  __syncthreads();
#pragma unroll
  for (int q = 0; q < 2; ++q) {
    float4 w = {o[4 * q], o[4 * q + 1], o[4 * q + 2], o[4 * q + 3]};
    *(float4*)&pool[lane * 84 + f0 + 4 * q] = w;
  }
  __syncthreads();
#pragma unroll
  for (int r = 0; r < 8; ++r) {
    int n = r * 8 + wv;
    int nj = base + n;
    if (nj < nN) out[(size_t)nj * 64 + lane] = pool[n * 84 + lane];
  }
}

extern "C" void kernel_launch(void* const* d_in, const int* in_sizes, int n_in,
                              void* d_out, int out_size, void* d_ws, size_t ws_size,
                              hipStream_t stream) {
  const float* x = (const float*)d_in[0];
  const void* edges = d_in[1];
  const float* conv_wl = (const float*)d_in[2];
  const float* conv_bl = (const float*)d_in[3];
  const float* conv_wr = (const float*)d_in[4];
  const float* ln_g = (const float*)d_in[5];
  const float* ln_b = (const float*)d_in[6];
  const float* adapter_w = (const float*)d_in[7];
  const float* adapter_b = (const float*)d_in[8];
  const float* mlp_w1 = (const float*)d_in[9];
  const float* mlp_b1 = (const float*)d_in[10];
  const float* mlp_lng = (const float*)d_in[11];
  const float* mlp_lnb = (const float*)d_in[12];
  const float* mlp_w2 = (const float*)d_in[13];
  const float* mlp_b2 = (const float*)d_in[14];

  const int N = in_sizes[0] / 64;
  const int E = in_sizes[1] / 2;
  const int NL = in_sizes[2] / (64 * 128);  // 5

  const int Na = (N + 63) & ~63;
  const int Ea = (E + 63) & ~63;
  int* deg = (int*)d_ws;
  int* cursor = deg + Na;
  int* row_start = cursor + Na;
  int* csr_src = row_start + (Na + 64);
  int* flag = csr_src + (Ea + 256);  // pad beyond E for clamped preloads
  int* bsum = flag + 64;
  float* wt_all = (float*)(bsum + 1024);
  float* awt = wt_all + (size_t)NL * 192 * 64;
  float* w1t = awt + 64 * 64;
  float* w2t = w1t + 64 * 256;
  float* h_ws = w2t + 256 * 64;
  float* outf = (float*)d_out;

  hipMemsetAsync(deg, 0, (size_t)N * 4, stream);
  hipMemsetAsync(cursor, 0, (size_t)N * 4, stream);

  detect_idx64<<<1, 64, 0, stream>>>((const unsigned*)edges, flag);
  count_deg<<<1024, 256, 0, stream>>>(edges, flag, deg, E);

  const int nsb = (N + 255) / 256;
  deg_block_sum<<<nsb, 256, 0, stream>>>(deg, bsum, N);
  scan_bsum<<<1, 1024, 0, stream>>>(bsum, nsb);
  scan_final<<<nsb, 256, 0, stream>>>(deg, bsum, row_start, N, E);

  fill_csr<<<1024, 256, 0, stream>>>(edges, flag, row_start, cursor, csr_src, E);

  int prep_tot = NL * 192 * 64 + 64 * 64 + 64 * 256 + 256 * 64;
  prep_weights<<<(prep_tot + 255) / 256, 256, 0, stream>>>(
      conv_wl, conv_wr, adapter_w, mlp_w1, mlp_w2, wt_all, awt, w1t, w2t, NL);

  const int nb = (N + 63) / 64;
  const float* src = x;
  for (int i = 0; i < NL; ++i) {
    float* dst = (((NL - i) & 1) == 1) ? h_ws : outf;
    const float* wt = wt_all + (size_t)i * 192 * 64;
    const float* bl = conv_bl + (size_t)i * 64;
    const float* g = ln_g + (size_t)i * 64;
    const float* b = ln_b + (size_t)i * 64;
    if (i == 0) {
      sage_layer<true><<<nb, 256, 0, stream>>>(src, dst, row_start, csr_src, wt, awt,
                                               bl, adapter_b, g, b, N);
    } else {
      sage_layer<false><<<nb, 256, 0, stream>>>(src, dst, row_start, csr_src, wt, awt,
                                                bl, adapter_b, g, b, N);
    }
    src = dst;
  }
  mlp_head<<<nb, 512, 0, stream>>>(src, outf, w1t, mlp_b1, mlp_lng, mlp_lnb, w2t, mlp_b2, N);
}

// Round 5
// 729.676 us; speedup vs baseline: 2.2478x; 1.2728x over previous
//
#include <hip/hip_runtime.h>

// SAGEEncoder v5: bf16 gather mirror (fp32 residual chain in-place in d_out),
// shfl-based idx broadcast (no idx LDS -> 3 blocks/CU), 16-edge load batches.

#define INFF 3.402823466e38f

__device__ __forceinline__ unsigned short f2bf(float f) {
  unsigned u = __float_as_uint(f);
  u = (u + 0x7FFFu + ((u >> 16) & 1u)) >> 16;
  return (unsigned short)u;
}

// ---- edge dtype detection: int64 iff the first 32 odd u32 slots are all zero ----
__global__ void detect_idx64(const unsigned* __restrict__ e, int* __restrict__ flag) {
  if (threadIdx.x == 0 && blockIdx.x == 0) {
    int is64 = 1;
    for (int i = 0; i < 32; ++i)
      if (e[2 * i + 1] != 0u) { is64 = 0; break; }
    *flag = is64;
  }
}

__device__ __forceinline__ int edge_val(const void* e, int is64, long long idx) {
  if (is64) return (int)((const long long*)e)[idx];
  return ((const int*)e)[idx];
}

__global__ void count_deg(const void* __restrict__ edges, const int* __restrict__ flag,
                          int* __restrict__ deg, int nE) {
  int is64 = *flag;
  long long E = nE;
  for (int i = blockIdx.x * blockDim.x + threadIdx.x; i < nE; i += gridDim.x * blockDim.x) {
    int dst = edge_val(edges, is64, E + i);
    atomicAdd(&deg[dst], 1);
  }
}

// ---- coalesced 3-phase exclusive scan ----
__global__ void deg_block_sum(const int* __restrict__ deg, int* __restrict__ bsum, int n) {
  __shared__ int w[4];
  int i = blockIdx.x * 256 + threadIdx.x;
  int v = (i < n) ? deg[i] : 0;
#pragma unroll
  for (int off = 32; off >= 1; off >>= 1) v += __shfl_down(v, off);
  if ((threadIdx.x & 63) == 0) w[threadIdx.x >> 6] = v;
  __syncthreads();
  if (threadIdx.x == 0) bsum[blockIdx.x] = w[0] + w[1] + w[2] + w[3];
}

__global__ void scan_bsum(int* __restrict__ bsum, int nb) {
  __shared__ int s[1024];
  int t = threadIdx.x;
  int v = (t < nb) ? bsum[t] : 0;
  s[t] = v;
  __syncthreads();
  for (int off = 1; off < 1024; off <<= 1) {
    int u = (t >= off) ? s[t - off] : 0;
    __syncthreads();
    s[t] += u;
    __syncthreads();
  }
  if (t < nb) bsum[t] = s[t] - v;  // exclusive
}

__global__ void scan_final(const int* __restrict__ deg, const int* __restrict__ bsum,
                           int* __restrict__ row_start, int n, int nE) {
  __shared__ int s[256];
  int t = threadIdx.x;
  int i = blockIdx.x * 256 + t;
  int v = (i < n) ? deg[i] : 0;
  s[t] = v;
  __syncthreads();
  int acc = v;
  for (int off = 1; off < 256; off <<= 1) {
    int u = (t >= off) ? s[t - off] : 0;
    __syncthreads();
    acc += u;
    s[t] = acc;
    __syncthreads();
  }
  if (i < n) row_start[i] = acc - v + bsum[blockIdx.x];
  if (i == n) row_start[n] = nE;
}

__global__ void fill_csr(const void* __restrict__ edges, const int* __restrict__ flag,
                         const int* __restrict__ row_start, int* __restrict__ cursor,
                         int* __restrict__ csr_src, int nE) {
  int is64 = *flag;
  long long E = nE;
  for (int i = blockIdx.x * blockDim.x + threadIdx.x; i < nE; i += gridDim.x * blockDim.x) {
    int src = edge_val(edges, is64, i);
    int dst = edge_val(edges, is64, E + i);
    int p = atomicAdd(&cursor[dst], 1);
    csr_src[row_start[dst] + p] = src;
  }
}

// ---- precompute transposed weights ----
__global__ void prep_weights(const float* __restrict__ wl, const float* __restrict__ wr,
                             const float* __restrict__ aw, const float* __restrict__ w1,
                             const float* __restrict__ w2,
                             float* __restrict__ wt, float* __restrict__ awt,
                             float* __restrict__ w1t, float* __restrict__ w2t, int nl) {
  int i = blockIdx.x * 256 + threadIdx.x;
  int tot_wt = nl * 192 * 64;
  if (i < tot_wt) {
    int l = i / (192 * 64);
    int r = i % (192 * 64);
    int k = r >> 6, f = r & 63;
    wt[i] = (k < 128) ? wl[(size_t)l * 64 * 128 + f * 128 + k]
                      : wr[(size_t)l * 64 * 64 + f * 64 + (k - 128)];
  } else {
    int j = i - tot_wt;
    if (j < 64 * 64) {
      int k = j >> 6, f = j & 63;
      awt[j] = aw[f * 64 + k];
    } else if (j < 64 * 64 + 64 * 256) {
      int q = j - 64 * 64;
      int k = q >> 8, p = q & 255;
      w1t[q] = w1[p * 64 + k];
    } else if (j < 64 * 64 + 64 * 256 + 256 * 64) {
      int q = j - 64 * 64 - 64 * 256;
      int k = q >> 6, f = q & 63;
      w2t[q] = w2[f * 256 + k];
    }
  }
}

__global__ void f32_to_bf16_k(const float* __restrict__ in, unsigned short* __restrict__ out,
                              int n4) {
  int stride = gridDim.x * blockDim.x;
  for (int i = blockIdx.x * blockDim.x + threadIdx.x; i < n4; i += stride) {
    float4 v = ((const float4*)in)[i];
    ushort4 o;
    o.x = f2bf(v.x); o.y = f2bf(v.y); o.z = f2bf(v.z); o.w = f2bf(v.w);
    ((ushort4*)out)[i] = o;
  }
}

// ---- fused SAGE layer ----
// Block: 256 threads (4 waves), 64 nodes. Gather from bf16 mirror (128B rows),
// fp32 self/residual from inf (in-place safe: row-local). 52.2KB LDS -> 3 blk/CU.
#define AS 196  // agg row stride in floats (49 quads, odd -> conflict-free b128)
template <bool FIRST>
__global__ __launch_bounds__(256, 3) void sage_layer(
    const float* __restrict__ inf, const unsigned short* __restrict__ inb,
    float* __restrict__ outf, unsigned short* __restrict__ outb,
    const int* __restrict__ row_start, const int* __restrict__ csr_src,
    const float* __restrict__ wt,    // [192][64]
    const float* __restrict__ awt,   // [64][64]
    const float* __restrict__ bl, const float* __restrict__ ab,
    const float* __restrict__ lng, const float* __restrict__ lnb,
    int nN) {
  __shared__ float lds[12544 + 512];  // agg[64][196] | ln1[256] ln2[256]
  float* agg = lds;
  float* ln1 = lds + 12544;
  float* ln2 = ln1 + 256;

  int t = threadIdx.x;
  int wv = __builtin_amdgcn_readfirstlane(t >> 6);
  int lane = t & 63;
  int g_lane = lane >> 4;          // node-slot group 0..3
  int fq4 = (lane & 15) * 4;       // feature quad base
  int foff = fq4 * 2;              // byte offset into bf16 row
  int base = blockIdx.x * 64;
  int wn0 = base + wv * 16;

  // ---- uniform row bounds (scalar) ----
  int rs[17];
#pragma unroll
  for (int i = 0; i <= 16; ++i) rs[i] = row_start[min(wn0 + i, nN)];

  // ---- per-lane node bounds for the 4 groups ----
  int offL[4], dgL[4], dgmL[4];
#pragma unroll
  for (int G = 0; G < 4; ++G) {
    int nj = wn0 + G * 4 + g_lane;
    int a = row_start[min(nj, nN)];
    int b = row_start[min(nj + 1, nN)];
    offL[G] = a - rs[4 * G];
    dgL[G] = b - a;
    dgmL[G] = max(dgL[G] - 1, 0);
  }

  // ---- preload neighbor indices into VGPRs (clamped; broadcast via shfl) ----
  int ivA[4], ivB[4];
#pragma unroll
  for (int G = 0; G < 4; ++G) {
    int Eg = rs[4 * G];
    int lenm1 = max(rs[4 * G + 4] - Eg - 1, 0);
    ivA[G] = min((unsigned)csr_src[Eg + min(lane, lenm1)], (unsigned)(nN - 1));
    ivB[G] = min((unsigned)csr_src[Eg + min(lane + 64, lenm1)], (unsigned)(nN - 1));
  }

  // ---- stage fp32 self rows (read-before-write for in-place outf==inf) ----
#pragma unroll
  for (int R = 0; R < 4; ++R) {
    int nloc = R * 4 + g_lane;
    int nj = wn0 + nloc;
    bool ok = nj < nN;
    unsigned njc = min((unsigned)nj, (unsigned)(nN - 1));
    float4 xv = *(const float4*)(inf + njc * 64u + fq4);
    if (!ok) xv = make_float4(0.f, 0.f, 0.f, 0.f);
    *(float4*)&agg[(wv * 16 + nloc) * AS + 128 + fq4] = xv;
  }

  // ---- gather (bf16): 4 nodes lockstep, 16 edges per batch ----
#pragma unroll
  for (int G = 0; G < 4; ++G) {
    int Eg = rs[4 * G];
    int len = rs[4 * G + 4] - Eg;
    int d0 = rs[4 * G + 1] - rs[4 * G + 0], d1 = rs[4 * G + 2] - rs[4 * G + 1];
    int d2 = rs[4 * G + 3] - rs[4 * G + 2], d3 = rs[4 * G + 4] - rs[4 * G + 3];
    int mm = max(max(d0, d1), max(d2, d3));
    int offl = offL[G], dgl = dgL[G], dgml = dgmL[G];
    float4 mx = make_float4(-INFF, -INFF, -INFF, -INFF);
    float4 sm = make_float4(0.f, 0.f, 0.f, 0.f);

    if (len <= 64) {
      for (int tt = 0; tt < mm; tt += 16) {
        uint2 v[16];
#pragma unroll
        for (int u = 0; u < 16; ++u) {
          int p = offl + min(tt + u, dgml);
          int si = __shfl(ivA[G], p);
          v[u] = *(const uint2*)((const char*)inb + ((si << 7) + foff));
        }
#pragma unroll
        for (int u = 0; u < 16; ++u) {
          float f0 = __uint_as_float(v[u].x << 16);
          float f1 = __uint_as_float(v[u].x & 0xFFFF0000u);
          float f2 = __uint_as_float(v[u].y << 16);
          float f3 = __uint_as_float(v[u].y & 0xFFFF0000u);
          float m = (tt + u < dgl) ? 1.f : 0.f;
          mx.x = fmaxf(mx.x, f0); mx.y = fmaxf(mx.y, f1);
          mx.z = fmaxf(mx.z, f2); mx.w = fmaxf(mx.w, f3);
          sm.x = fmaf(f0, m, sm.x); sm.y = fmaf(f1, m, sm.y);
          sm.z = fmaf(f2, m, sm.z); sm.w = fmaf(f3, m, sm.w);
        }
      }
    } else if (len <= 128) {
      for (int tt = 0; tt < mm; tt += 8) {
        uint2 v[8];
#pragma unroll
        for (int u = 0; u < 8; ++u) {
          int p = offl + min(tt + u, dgml);
          int a = __shfl(ivA[G], p & 63);
          int b = __shfl(ivB[G], p & 63);
          int si = (p < 64) ? a : b;
          v[u] = *(const uint2*)((const char*)inb + ((si << 7) + foff));
        }
#pragma unroll
        for (int u = 0; u < 8; ++u) {
          float f0 = __uint_as_float(v[u].x << 16);
          float f1 = __uint_as_float(v[u].x & 0xFFFF0000u);
          float f2 = __uint_as_float(v[u].y << 16);
          float f3 = __uint_as_float(v[u].y & 0xFFFF0000u);
          float m = (tt + u < dgl) ? 1.f : 0.f;
          mx.x = fmaxf(mx.x, f0); mx.y = fmaxf(mx.y, f1);
          mx.z = fmaxf(mx.z, f2); mx.w = fmaxf(mx.w, f3);
          sm.x = fmaf(f0, m, sm.x); sm.y = fmaf(f1, m, sm.y);
          sm.z = fmaf(f2, m, sm.z); sm.w = fmaf(f3, m, sm.w);
        }
      }
    } else {  // very rare: >128 edges in a 4-node group
      for (int tt = 0; tt < mm; tt += 4) {
        uint2 v[4];
#pragma unroll
        for (int u = 0; u < 4; ++u) {
          int p = offl + min(tt + u, dgml);
          unsigned si = min((unsigned)csr_src[Eg + p], (unsigned)(nN - 1));
          v[u] = *(const uint2*)((const char*)inb + (((int)si << 7) + foff));
        }
#pragma unroll
        for (int u = 0; u < 4; ++u) {
          float f0 = __uint_as_float(v[u].x << 16);
          float f1 = __uint_as_float(v[u].x & 0xFFFF0000u);
          float f2 = __uint_as_float(v[u].y << 16);
          float f3 = __uint_as_float(v[u].y & 0xFFFF0000u);
          float m = (tt + u < dgl) ? 1.f : 0.f;
          mx.x = fmaxf(mx.x, f0); mx.y = fmaxf(mx.y, f1);
          mx.z = fmaxf(mx.z, f2); mx.w = fmaxf(mx.w, f3);
          sm.x = fmaf(f0, m, sm.x); sm.y = fmaf(f1, m, sm.y);
          sm.z = fmaf(f2, m, sm.z); sm.w = fmaf(f3, m, sm.w);
        }
      }
    }

    int nloc = wv * 16 + G * 4 + g_lane;
    float4 ax;
    ax.x = (dgl > 0) ? mx.x : 0.f; ax.y = (dgl > 0) ? mx.y : 0.f;
    ax.z = (dgl > 0) ? mx.z : 0.f; ax.w = (dgl > 0) ? mx.w : 0.f;
    float r = 1.f / (float)max(dgl, 1);
    float4 am = make_float4(sm.x * r, sm.y * r, sm.z * r, sm.w * r);
    *(float4*)&agg[nloc * AS + fq4] = ax;
    *(float4*)&agg[nloc * AS + 64 + fq4] = am;
  }
  __syncthreads();

  // ---- Phase 2: GEMM. lane = node, wave owns features f0..f0+15. ----
  int f0 = __builtin_amdgcn_readfirstlane(wv * 16);
  float acc[16], accr[16];
#pragma unroll
  for (int i = 0; i < 16; ++i) { acc[i] = 0.f; accr[i] = 0.f; }
  for (int kc = 0; kc < 192; kc += 4) {
    float4 av = *(const float4*)&agg[lane * AS + kc];
    float a4[4] = {av.x, av.y, av.z, av.w};
#pragma unroll
    for (int q = 0; q < 4; ++q) {
      int k = kc + q;
      const float* wrow = wt + k * 64 + f0;
#pragma unroll
      for (int i = 0; i < 16; ++i) acc[i] = fmaf(a4[q], wrow[i], acc[i]);
      if (FIRST) {
        if (k >= 128) {
          const float* arow = awt + (k - 128) * 64 + f0;
#pragma unroll
          for (int i = 0; i < 16; ++i) accr[i] = fmaf(a4[q], arow[i], accr[i]);
        }
      }
    }
  }

  // ---- Phase 3: bias, LN, residual, SiLU, store (fp32 + bf16 mirror) ----
#pragma unroll
  for (int i = 0; i < 16; ++i) acc[i] += bl[f0 + i];
  float s1 = 0.f, s2 = 0.f;
#pragma unroll
  for (int i = 0; i < 16; ++i) { s1 += acc[i]; s2 = fmaf(acc[i], acc[i], s2); }
  ln1[wv * 64 + lane] = s1;
  ln2[wv * 64 + lane] = s2;
  __syncthreads();
  float t1 = (ln1[lane] + ln1[64 + lane]) + (ln1[128 + lane] + ln1[192 + lane]);
  float t2 = (ln2[lane] + ln2[64 + lane]) + (ln2[128 + lane] + ln2[192 + lane]);
  float mean = t1 * 0.015625f;
  float var = t2 * 0.015625f - mean * mean;
  float rs_ = rsqrtf(var + 1e-5f);

  float res[16];
  if (FIRST) {
#pragma unroll
    for (int i = 0; i < 16; ++i) res[i] = accr[i] + ab[f0 + i];
  } else {
#pragma unroll
    for (int q = 0; q < 4; ++q) {
      float4 rv = *(const float4*)&agg[lane * AS + 128 + f0 + 4 * q];
      res[4 * q + 0] = rv.x; res[4 * q + 1] = rv.y; res[4 * q + 2] = rv.z; res[4 * q + 3] = rv.w;
    }
  }
  float y[16];
#pragma unroll
  for (int i = 0; i < 16; ++i) {
    float v = (acc[i] - mean) * rs_ * lng[f0 + i] + lnb[f0 + i] + res[i];
    y[i] = v / (1.f + __expf(-v));
  }
  __syncthreads();  // all residual reads of agg done before overwrite
#pragma unroll
  for (int q = 0; q < 4; ++q) {
    float4 w = {y[4 * q], y[4 * q + 1], y[4 * q + 2], y[4 * q + 3]};
    *(float4*)&agg[lane * AS + f0 + 4 * q] = w;
  }
  __syncthreads();
#pragma unroll
  for (int r = 0; r < 16; ++r) {
    int nl_ = r * 4 + wv;
    int nj = base + nl_;
    if (nj < nN) {
      float yv = agg[nl_ * AS + lane];
      outf[(size_t)nj * 64 + lane] = yv;
      outb[(size_t)nj * 64 + lane] = f2bf(yv);
    }
  }
}

// ---- MLP head (in-place on d_out; strides 84/276 odd-quad) ----
__global__ __launch_bounds__(512, 2) void mlp_head(
    const float* __restrict__ in, float* __restrict__ out,
    const float* __restrict__ w1t, const float* __restrict__ b1,
    const float* __restrict__ lng, const float* __restrict__ lnb,
    const float* __restrict__ w2t, const float* __restrict__ b2, int nN) {
  __shared__ float pool[64 * 276 + 1024];
  float* ln1 = pool + 64 * 276;
  float* ln2 = ln1 + 512;

  int t = threadIdx.x;
  int wv = __builtin_amdgcn_readfirstlane(t >> 6);
  int lane = t & 63;
  int base = blockIdx.x * 64;

#pragma unroll
  for (int r = 0; r < 8; ++r) {
    int n = r * 8 + wv;
    int nj = base + n;
    pool[n * 84 + lane] = (nj < nN) ? in[(size_t)nj * 64 + lane] : 0.f;
  }
  __syncthreads();

  int p0 = __builtin_amdgcn_readfirstlane(wv * 32);
  float u[32];
#pragma unroll
  for (int i = 0; i < 32; ++i) u[i] = 0.f;
  for (int kc = 0; kc < 64; kc += 4) {
    float4 av = *(const float4*)&pool[lane * 84 + kc];
    float a4[4] = {av.x, av.y, av.z, av.w};
#pragma unroll
    for (int q = 0; q < 4; ++q) {
      const float* wrow = w1t + (kc + q) * 256 + p0;
#pragma unroll
      for (int i = 0; i < 32; ++i) u[i] = fmaf(a4[q], wrow[i], u[i]);
    }
  }
#pragma unroll
  for (int i = 0; i < 32; ++i) {
    float v = u[i] + b1[p0 + i];
    u[i] = v / (1.f + __expf(-v));
  }
  float s1 = 0.f, s2 = 0.f;
#pragma unroll
  for (int i = 0; i < 32; ++i) { s1 += u[i]; s2 = fmaf(u[i], u[i], s2); }
  ln1[wv * 64 + lane] = s1;
  ln2[wv * 64 + lane] = s2;
  __syncthreads();
  float t1 = 0.f, t2 = 0.f;
#pragma unroll
  for (int w = 0; w < 8; ++w) { t1 += ln1[w * 64 + lane]; t2 += ln2[w * 64 + lane]; }
  float mean = t1 * 0.00390625f;
  float var = t2 * 0.00390625f - mean * mean;
  float rs_ = rsqrtf(var + 1e-5f);
#pragma unroll
  for (int i = 0; i < 32; ++i) u[i] = (u[i] - mean) * rs_ * lng[p0 + i] + lnb[p0 + i];
#pragma unroll
  for (int q = 0; q < 8; ++q) {
    float4 w = {u[4 * q], u[4 * q + 1], u[4 * q + 2], u[4 * q + 3]};
    *(float4*)&pool[lane * 276 + p0 + 4 * q] = w;
  }
  __syncthreads();

  int f0 = __builtin_amdgcn_readfirstlane(wv * 8);
  float o[8];
#pragma unroll
  for (int i = 0; i < 8; ++i) o[i] = 0.f;
  for (int kc = 0; kc < 256; kc += 4) {
    float4 av = *(const float4*)&pool[lane * 276 + kc];
    float a4[4] = {av.x, av.y, av.z, av.w};
#pragma unroll
    for (int q = 0; q < 4; ++q) {
      const float* wrow = w2t + (kc + q) * 64 + f0;
#pragma unroll
      for (int i = 0; i < 8; ++i) o[i] = fmaf(a4[q], wrow[i], o[i]);
    }
  }
#pragma unroll
  for (int i = 0; i < 8; ++i) o[i] += b2[f0 + i];
  __syncthreads();
#pragma unroll
  for (int q = 0; q < 2; ++q) {
    float4 w = {o[4 * q], o[4 * q + 1], o[4 * q + 2], o[4 * q + 3]};
    *(float4*)&pool[lane * 84 + f0 + 4 * q] = w;
  }
  __syncthreads();
#pragma unroll
  for (int r = 0; r < 8; ++r) {
    int n = r * 8 + wv;
    int nj = base + n;
    if (nj < nN) out[(size_t)nj * 64 + lane] = pool[n * 84 + lane];
  }
}

extern "C" void kernel_launch(void* const* d_in, const int* in_sizes, int n_in,
                              void* d_out, int out_size, void* d_ws, size_t ws_size,
                              hipStream_t stream) {
  const float* x = (const float*)d_in[0];
  const void* edges = d_in[1];
  const float* conv_wl = (const float*)d_in[2];
  const float* conv_bl = (const float*)d_in[3];
  const float* conv_wr = (const float*)d_in[4];
  const float* ln_g = (const float*)d_in[5];
  const float* ln_b = (const float*)d_in[6];
  const float* adapter_w = (const float*)d_in[7];
  const float* adapter_b = (const float*)d_in[8];
  const float* mlp_w1 = (const float*)d_in[9];
  const float* mlp_b1 = (const float*)d_in[10];
  const float* mlp_lng = (const float*)d_in[11];
  const float* mlp_lnb = (const float*)d_in[12];
  const float* mlp_w2 = (const float*)d_in[13];
  const float* mlp_b2 = (const float*)d_in[14];

  const int N = in_sizes[0] / 64;
  const int E = in_sizes[1] / 2;
  const int NL = in_sizes[2] / (64 * 128);  // 5

  const int Na = (N + 63) & ~63;
  const int Ea = (E + 63) & ~63;
  int* deg = (int*)d_ws;
  int* cursor = deg + Na;
  int* row_start = cursor + Na;
  int* csr_src = row_start + (Na + 64);
  int* flag = csr_src + (Ea + 256);  // pad beyond E for clamped preloads
  int* bsum = flag + 64;
  float* wt_all = (float*)(bsum + 1024);
  float* awt = wt_all + (size_t)NL * 192 * 64;
  float* w1t = awt + 64 * 64;
  float* w2t = w1t + 64 * 256;
  unsigned short* b0 = (unsigned short*)(w2t + 256 * 64);
  unsigned short* b1 = b0 + (size_t)Na * 64;
  float* outf = (float*)d_out;

  hipMemsetAsync(deg, 0, (size_t)N * 4, stream);
  hipMemsetAsync(cursor, 0, (size_t)N * 4, stream);

  detect_idx64<<<1, 64, 0, stream>>>((const unsigned*)edges, flag);
  count_deg<<<1024, 256, 0, stream>>>(edges, flag, deg, E);

  const int nsb = (N + 255) / 256;
  deg_block_sum<<<nsb, 256, 0, stream>>>(deg, bsum, N);
  scan_bsum<<<1, 1024, 0, stream>>>(bsum, nsb);
  scan_final<<<nsb, 256, 0, stream>>>(deg, bsum, row_start, N, E);

  fill_csr<<<1024, 256, 0, stream>>>(edges, flag, row_start, cursor, csr_src, E);

  int prep_tot = NL * 192 * 64 + 64 * 64 + 64 * 256 + 256 * 64;
  prep_weights<<<(prep_tot + 255) / 256, 256, 0, stream>>>(
      conv_wl, conv_wr, adapter_w, mlp_w1, mlp_w2, wt_all, awt, w1t, w2t, NL);

  f32_to_bf16_k<<<1024, 256, 0, stream>>>(x, b0, N * 16);

  const int nb = (N + 63) / 64;
  for (int i = 0; i < NL; ++i) {
    const float* inf = (i == 0) ? x : outf;
    unsigned short* inb = (i & 1) ? b1 : b0;
    unsigned short* outb = (i & 1) ? b0 : b1;
    const float* wt = wt_all + (size_t)i * 192 * 64;
    const float* bl = conv_bl + (size_t)i * 64;
    const float* g = ln_g + (size_t)i * 64;
    const float* b = ln_b + (size_t)i * 64;
    if (i == 0) {
      sage_layer<true><<<nb, 256, 0, stream>>>(inf, inb, outf, outb, row_start, csr_src,
                                               wt, awt, bl, adapter_b, g, b, N);
    } else {
      sage_layer<false><<<nb, 256, 0, stream>>>(inf, inb, outf, outb, row_start, csr_src,
                                                wt, awt, bl, adapter_b, g, b, N);
    }
  }
  mlp_head<<<nb, 512, 0, stream>>>(outf, outf, w1t, mlp_b1, mlp_lng, mlp_lnb, w2t, mlp_b2, N);
}

// Round 6
// 605.289 us; speedup vs baseline: 2.7098x; 1.2055x over previous
//
#include <hip/hip_runtime.h>

// SAGEEncoder v6: bf16 LDS tiles for occupancy (sage 5 blk/CU, mlp 4 blk/CU),
// fp32 residual chain via global re-read, readlane row-bound preamble.

#define INFF 3.402823466e38f

__device__ __forceinline__ unsigned short f2bf(float f) {
  unsigned u = __float_as_uint(f);
  u = (u + 0x7FFFu + ((u >> 16) & 1u)) >> 16;
  return (unsigned short)u;
}
__device__ __forceinline__ unsigned pack2(float a, float b) {
  return (unsigned)f2bf(a) | ((unsigned)f2bf(b) << 16);
}
__device__ __forceinline__ float bf_lo(unsigned u) { return __uint_as_float(u << 16); }
__device__ __forceinline__ float bf_hi(unsigned u) { return __uint_as_float(u & 0xFFFF0000u); }

// ---- edge dtype detection: int64 iff the first 32 odd u32 slots are all zero ----
__global__ void detect_idx64(const unsigned* __restrict__ e, int* __restrict__ flag) {
  if (threadIdx.x == 0 && blockIdx.x == 0) {
    int is64 = 1;
    for (int i = 0; i < 32; ++i)
      if (e[2 * i + 1] != 0u) { is64 = 0; break; }
    *flag = is64;
  }
}

__device__ __forceinline__ int edge_val(const void* e, int is64, long long idx) {
  if (is64) return (int)((const long long*)e)[idx];
  return ((const int*)e)[idx];
}

__global__ void count_deg(const void* __restrict__ edges, const int* __restrict__ flag,
                          int* __restrict__ deg, int nE) {
  int is64 = *flag;
  long long E = nE;
  for (int i = blockIdx.x * blockDim.x + threadIdx.x; i < nE; i += gridDim.x * blockDim.x) {
    int dst = edge_val(edges, is64, E + i);
    atomicAdd(&deg[dst], 1);
  }
}

// ---- coalesced 3-phase exclusive scan ----
__global__ void deg_block_sum(const int* __restrict__ deg, int* __restrict__ bsum, int n) {
  __shared__ int w[4];
  int i = blockIdx.x * 256 + threadIdx.x;
  int v = (i < n) ? deg[i] : 0;
#pragma unroll
  for (int off = 32; off >= 1; off >>= 1) v += __shfl_down(v, off);
  if ((threadIdx.x & 63) == 0) w[threadIdx.x >> 6] = v;
  __syncthreads();
  if (threadIdx.x == 0) bsum[blockIdx.x] = w[0] + w[1] + w[2] + w[3];
}

__global__ void scan_bsum(int* __restrict__ bsum, int nb) {
  __shared__ int s[1024];
  int t = threadIdx.x;
  int v = (t < nb) ? bsum[t] : 0;
  s[t] = v;
  __syncthreads();
  for (int off = 1; off < 1024; off <<= 1) {
    int u = (t >= off) ? s[t - off] : 0;
    __syncthreads();
    s[t] += u;
    __syncthreads();
  }
  if (t < nb) bsum[t] = s[t] - v;  // exclusive
}

__global__ void scan_final(const int* __restrict__ deg, const int* __restrict__ bsum,
                           int* __restrict__ row_start, int n, int nE) {
  __shared__ int s[256];
  int t = threadIdx.x;
  int i = blockIdx.x * 256 + t;
  int v = (i < n) ? deg[i] : 0;
  s[t] = v;
  __syncthreads();
  int acc = v;
  for (int off = 1; off < 256; off <<= 1) {
    int u = (t >= off) ? s[t - off] : 0;
    __syncthreads();
    acc += u;
    s[t] = acc;
    __syncthreads();
  }
  if (i < n) row_start[i] = acc - v + bsum[blockIdx.x];
  if (i == n) row_start[n] = nE;
}

__global__ void fill_csr(const void* __restrict__ edges, const int* __restrict__ flag,
                         const int* __restrict__ row_start, int* __restrict__ cursor,
                         int* __restrict__ csr_src, int nE) {
  int is64 = *flag;
  long long E = nE;
  for (int i = blockIdx.x * blockDim.x + threadIdx.x; i < nE; i += gridDim.x * blockDim.x) {
    int src = edge_val(edges, is64, i);
    int dst = edge_val(edges, is64, E + i);
    int p = atomicAdd(&cursor[dst], 1);
    csr_src[row_start[dst] + p] = src;
  }
}

// ---- precompute transposed weights ----
__global__ void prep_weights(const float* __restrict__ wl, const float* __restrict__ wr,
                             const float* __restrict__ aw, const float* __restrict__ w1,
                             const float* __restrict__ w2,
                             float* __restrict__ wt, float* __restrict__ awt,
                             float* __restrict__ w1t, float* __restrict__ w2t, int nl) {
  int i = blockIdx.x * 256 + threadIdx.x;
  int tot_wt = nl * 192 * 64;
  if (i < tot_wt) {
    int l = i / (192 * 64);
    int r = i % (192 * 64);
    int k = r >> 6, f = r & 63;
    wt[i] = (k < 128) ? wl[(size_t)l * 64 * 128 + f * 128 + k]
                      : wr[(size_t)l * 64 * 64 + f * 64 + (k - 128)];
  } else {
    int j = i - tot_wt;
    if (j < 64 * 64) {
      int k = j >> 6, f = j & 63;
      awt[j] = aw[f * 64 + k];
    } else if (j < 64 * 64 + 64 * 256) {
      int q = j - 64 * 64;
      int k = q >> 8, p = q & 255;
      w1t[q] = w1[p * 64 + k];
    } else if (j < 64 * 64 + 64 * 256 + 256 * 64) {
      int q = j - 64 * 64 - 64 * 256;
      int k = q >> 6, f = q & 63;
      w2t[q] = w2[f * 256 + k];
    }
  }
}

__global__ void f32_to_bf16_k(const float* __restrict__ in, unsigned short* __restrict__ out,
                              int n4) {
  int stride = gridDim.x * blockDim.x;
  for (int i = blockIdx.x * blockDim.x + threadIdx.x; i < n4; i += stride) {
    float4 v = ((const float4*)in)[i];
    ushort4 o;
    o.x = f2bf(v.x); o.y = f2bf(v.y); o.z = f2bf(v.z); o.w = f2bf(v.w);
    ((ushort4*)out)[i] = o;
  }
}

// ---- fused SAGE layer ----
// Block: 256 threads (4 waves), 64 nodes. agg in bf16 (99-uint rows, odd dword
// stride), gather from bf16 mirror, fp32 residual re-read from global.
template <bool FIRST>
__global__ __launch_bounds__(256, 5) void sage_layer(
    const float* __restrict__ inf, const unsigned short* __restrict__ inb,
    float* __restrict__ outf, unsigned short* __restrict__ outb,
    const int* __restrict__ row_start, const int* __restrict__ csr_src,
    const float* __restrict__ wt,    // [192][64]
    const float* __restrict__ awt,   // [64][64]
    const float* __restrict__ bl, const float* __restrict__ ab,
    const float* __restrict__ lng, const float* __restrict__ lnb,
    int nN, int wf32) {
  __shared__ unsigned aggU[64 * 99];  // bf16 agg[64][198]: max|mean|x (cols 0/64/128)
  __shared__ float ln1[256], ln2[256];
  float* transf = (float*)aggU;  // overlay after GEMM: [64][68] fp32

  int t = threadIdx.x;
  int wv = __builtin_amdgcn_readfirstlane(t >> 6);
  int lane = t & 63;
  int g_lane = lane >> 4;      // node slot 0..3
  int fq4 = (lane & 15) * 4;   // feature quad base
  int foff = fq4 * 2;          // byte offset into bf16 row
  int base = blockIdx.x * 64;
  int wn0 = base + wv * 16;

  // ---- row bounds: one vector load + readlane/shfl ----
  int rlv = row_start[min(wn0 + min(lane, 16), nN)];
  int rs[17];
#pragma unroll
  for (int i = 0; i <= 16; ++i) rs[i] = __builtin_amdgcn_readlane(rlv, i);

  int offL[4], dgL[4], dgmL[4];
#pragma unroll
  for (int G = 0; G < 4; ++G) {
    int a_ = __shfl(rlv, 4 * G + g_lane);
    int b_ = __shfl(rlv, 4 * G + g_lane + 1);
    offL[G] = a_ - rs[4 * G];
    dgL[G] = b_ - a_;
    dgmL[G] = max(dgL[G] - 1, 0);
  }

  // ---- preload neighbor indices (clamped; broadcast via shfl) ----
  int ivA[4], ivB[4];
#pragma unroll
  for (int G = 0; G < 4; ++G) {
    int Eg = rs[4 * G];
    int lenm1 = max(rs[4 * G + 4] - Eg - 1, 0);
    ivA[G] = min((unsigned)csr_src[Eg + min(lane, lenm1)], (unsigned)(nN - 1));
    ivB[G] = min((unsigned)csr_src[Eg + min(lane + 64, lenm1)], (unsigned)(nN - 1));
  }

  // ---- stage self rows (fp32 read -> bf16 agg cols 128..191) ----
#pragma unroll
  for (int R = 0; R < 4; ++R) {
    int nloc = R * 4 + g_lane;
    int nj = wn0 + nloc;
    bool ok = nj < nN;
    unsigned njc = min((unsigned)nj, (unsigned)(nN - 1));
    float4 xv = *(const float4*)(inf + (size_t)njc * 64u + fq4);
    if (!ok) xv = make_float4(0.f, 0.f, 0.f, 0.f);
    int rowU = (wv * 16 + nloc) * 99;
    aggU[rowU + 64 + (fq4 >> 1)] = pack2(xv.x, xv.y);
    aggU[rowU + 64 + (fq4 >> 1) + 1] = pack2(xv.z, xv.w);
  }

  // ---- gather (bf16 mirror): 4 nodes lockstep, 16-edge batches ----
#pragma unroll
  for (int G = 0; G < 4; ++G) {
    int Eg = rs[4 * G];
    int len = rs[4 * G + 4] - Eg;
    int d0 = rs[4 * G + 1] - rs[4 * G + 0], d1 = rs[4 * G + 2] - rs[4 * G + 1];
    int d2 = rs[4 * G + 3] - rs[4 * G + 2], d3 = rs[4 * G + 4] - rs[4 * G + 3];
    int mm = max(max(d0, d1), max(d2, d3));
    int offl = offL[G], dgl = dgL[G], dgml = dgmL[G];
    float4 mx = make_float4(-INFF, -INFF, -INFF, -INFF);
    float4 sm = make_float4(0.f, 0.f, 0.f, 0.f);

    if (len <= 64) {
      for (int tt = 0; tt < mm; tt += 16) {
        uint2 v[16];
#pragma unroll
        for (int u = 0; u < 16; ++u) {
          int p = offl + min(tt + u, dgml);
          int si = __shfl(ivA[G], p);
          v[u] = *(const uint2*)((const char*)inb + ((si << 7) + foff));
        }
#pragma unroll
        for (int u = 0; u < 16; ++u) {
          float f0 = bf_lo(v[u].x), f1 = bf_hi(v[u].x);
          float f2 = bf_lo(v[u].y), f3 = bf_hi(v[u].y);
          float m = (tt + u < dgl) ? 1.f : 0.f;
          mx.x = fmaxf(mx.x, f0); mx.y = fmaxf(mx.y, f1);
          mx.z = fmaxf(mx.z, f2); mx.w = fmaxf(mx.w, f3);
          sm.x = fmaf(f0, m, sm.x); sm.y = fmaf(f1, m, sm.y);
          sm.z = fmaf(f2, m, sm.z); sm.w = fmaf(f3, m, sm.w);
        }
      }
    } else if (len <= 128) {
      for (int tt = 0; tt < mm; tt += 8) {
        uint2 v[8];
#pragma unroll
        for (int u = 0; u < 8; ++u) {
          int p = offl + min(tt + u, dgml);
          int a = __shfl(ivA[G], p & 63);
          int b = __shfl(ivB[G], p & 63);
          int si = (p < 64) ? a : b;
          v[u] = *(const uint2*)((const char*)inb + ((si << 7) + foff));
        }
#pragma unroll
        for (int u = 0; u < 8; ++u) {
          float f0 = bf_lo(v[u].x), f1 = bf_hi(v[u].x);
          float f2 = bf_lo(v[u].y), f3 = bf_hi(v[u].y);
          float m = (tt + u < dgl) ? 1.f : 0.f;
          mx.x = fmaxf(mx.x, f0); mx.y = fmaxf(mx.y, f1);
          mx.z = fmaxf(mx.z, f2); mx.w = fmaxf(mx.w, f3);
          sm.x = fmaf(f0, m, sm.x); sm.y = fmaf(f1, m, sm.y);
          sm.z = fmaf(f2, m, sm.z); sm.w = fmaf(f3, m, sm.w);
        }
      }
    } else {  // very rare
      for (int tt = 0; tt < mm; tt += 4) {
        uint2 v[4];
#pragma unroll
        for (int u = 0; u < 4; ++u) {
          int p = offl + min(tt + u, dgml);
          unsigned si = min((unsigned)csr_src[Eg + p], (unsigned)(nN - 1));
          v[u] = *(const uint2*)((const char*)inb + (((int)si << 7) + foff));
        }
#pragma unroll
        for (int u = 0; u < 4; ++u) {
          float f0 = bf_lo(v[u].x), f1 = bf_hi(v[u].x);
          float f2 = bf_lo(v[u].y), f3 = bf_hi(v[u].y);
          float m = (tt + u < dgl) ? 1.f : 0.f;
          mx.x = fmaxf(mx.x, f0); mx.y = fmaxf(mx.y, f1);
          mx.z = fmaxf(mx.z, f2); mx.w = fmaxf(mx.w, f3);
          sm.x = fmaf(f0, m, sm.x); sm.y = fmaf(f1, m, sm.y);
          sm.z = fmaf(f2, m, sm.z); sm.w = fmaf(f3, m, sm.w);
        }
      }
    }

    int rowU = (wv * 16 + G * 4 + g_lane) * 99;
    float ok = (dgl > 0) ? 1.f : 0.f;
    float r = 1.f / (float)max(dgl, 1);
    aggU[rowU + (fq4 >> 1)] = pack2(ok * mx.x, ok * mx.y);
    aggU[rowU + (fq4 >> 1) + 1] = pack2(ok * mx.z, ok * mx.w);
    aggU[rowU + 32 + (fq4 >> 1)] = pack2(sm.x * r, sm.y * r);
    aggU[rowU + 32 + (fq4 >> 1) + 1] = pack2(sm.z * r, sm.w * r);
  }
  __syncthreads();

  // ---- Phase 2: GEMM. lane = node, wave owns features f0..f0+15 ----
  int f0 = __builtin_amdgcn_readfirstlane(wv * 16);
  float acc[16], accr[16];
#pragma unroll
  for (int i = 0; i < 16; ++i) { acc[i] = 0.f; accr[i] = 0.f; }
  int rbase = lane * 99;
  for (int kc = 0; kc < 192; kc += 4) {
    unsigned a01 = aggU[rbase + (kc >> 1)];
    unsigned a23 = aggU[rbase + (kc >> 1) + 1];
    float a4[4] = {bf_lo(a01), bf_hi(a01), bf_lo(a23), bf_hi(a23)};
#pragma unroll
    for (int q = 0; q < 4; ++q) {
      int k = kc + q;
      const float* wrow = wt + k * 64 + f0;
#pragma unroll
      for (int i = 0; i < 16; ++i) acc[i] = fmaf(a4[q], wrow[i], acc[i]);
      if (FIRST) {
        if (k >= 128) {
          const float* arow = awt + (k - 128) * 64 + f0;
#pragma unroll
          for (int i = 0; i < 16; ++i) accr[i] = fmaf(a4[q], arow[i], accr[i]);
        }
      }
    }
  }

  // ---- Phase 3: bias, LN, residual (fp32 re-read), SiLU, store ----
#pragma unroll
  for (int i = 0; i < 16; ++i) acc[i] += bl[f0 + i];
  float s1 = 0.f, s2 = 0.f;
#pragma unroll
  for (int i = 0; i < 16; ++i) { s1 += acc[i]; s2 = fmaf(acc[i], acc[i], s2); }
  ln1[wv * 64 + lane] = s1;
  ln2[wv * 64 + lane] = s2;
  __syncthreads();
  float t1 = (ln1[lane] + ln1[64 + lane]) + (ln1[128 + lane] + ln1[192 + lane]);
  float t2 = (ln2[lane] + ln2[64 + lane]) + (ln2[128 + lane] + ln2[192 + lane]);
  float mean = t1 * 0.015625f;
  float var = t2 * 0.015625f - mean * mean;
  float rs_ = rsqrtf(var + 1e-5f);

  float res[16];
  if (FIRST) {
#pragma unroll
    for (int i = 0; i < 16; ++i) res[i] = accr[i] + ab[f0 + i];
  } else {
    unsigned njc = min((unsigned)(base + lane), (unsigned)(nN - 1));
    const float* rp = inf + (size_t)njc * 64u + f0;
#pragma unroll
    for (int q = 0; q < 4; ++q) {
      float4 rv = *(const float4*)(rp + 4 * q);
      res[4 * q + 0] = rv.x; res[4 * q + 1] = rv.y; res[4 * q + 2] = rv.z; res[4 * q + 3] = rv.w;
    }
  }
  float y[16];
#pragma unroll
  for (int i = 0; i < 16; ++i) {
    float v = (acc[i] - mean) * rs_ * lng[f0 + i] + lnb[f0 + i] + res[i];
    y[i] = v / (1.f + __expf(-v));
  }
  // transpose via overlaid fp32 region (all agg reads completed before LN barrier)
#pragma unroll
  for (int q = 0; q < 4; ++q) {
    float4 w = {y[4 * q], y[4 * q + 1], y[4 * q + 2], y[4 * q + 3]};
    *(float4*)&transf[lane * 68 + f0 + 4 * q] = w;
  }
  __syncthreads();
#pragma unroll
  for (int r = 0; r < 16; ++r) {
    int nl_ = r * 4 + wv;
    int nj = base + nl_;
    if (nj < nN) {
      float yv = transf[nl_ * 68 + lane];
      if (wf32) outf[(size_t)nj * 64 + lane] = yv;
      outb[(size_t)nj * 64 + lane] = f2bf(yv);
    }
  }
}

// ---- MLP head: bf16 staging, 4 blocks/CU ----
__global__ __launch_bounds__(512, 8) void mlp_head(
    const unsigned short* __restrict__ inb, float* __restrict__ out,
    const float* __restrict__ w1t, const float* __restrict__ b1v,
    const float* __restrict__ lng, const float* __restrict__ lnb,
    const float* __restrict__ w2t, const float* __restrict__ b2, int nN) {
  __shared__ unsigned poolU[64 * 137];  // hb[64][41u] then ub[64][137u] overlay
  __shared__ float ln1[512], ln2[512];
  float* transf = (float*)poolU;

  int t = threadIdx.x;
  int wv = __builtin_amdgcn_readfirstlane(t >> 6);
  int lane = t & 63;
  int base = blockIdx.x * 64;

  // stage h rows from bf16 mirror (32 uints per row, 2 rows per wave per iter)
  const unsigned* inb32 = (const unsigned*)inb;
#pragma unroll
  for (int r = 0; r < 4; ++r) {
    int n = r * 16 + wv * 2 + (lane >> 5);
    int nj = base + n;
    unsigned v = (nj < nN) ? inb32[(size_t)nj * 32 + (lane & 31)] : 0u;
    poolU[n * 41 + (lane & 31)] = v;
  }
  __syncthreads();

  // GEMM1: u[p0..p0+31] per wave, lane=node
  int p0 = __builtin_amdgcn_readfirstlane(wv * 32);
  float u[32];
#pragma unroll
  for (int i = 0; i < 32; ++i) u[i] = 0.f;
  int hbase = lane * 41;
  for (int kc = 0; kc < 64; kc += 4) {
    unsigned h01 = poolU[hbase + (kc >> 1)];
    unsigned h23 = poolU[hbase + (kc >> 1) + 1];
    float a4[4] = {bf_lo(h01), bf_hi(h01), bf_lo(h23), bf_hi(h23)};
#pragma unroll
    for (int q = 0; q < 4; ++q) {
      const float* wrow = w1t + (kc + q) * 256 + p0;
#pragma unroll
      for (int i = 0; i < 32; ++i) u[i] = fmaf(a4[q], wrow[i], u[i]);
    }
  }
#pragma unroll
  for (int i = 0; i < 32; ++i) {
    float v = u[i] + b1v[p0 + i];
    u[i] = v / (1.f + __expf(-v));
  }
  float s1 = 0.f, s2 = 0.f;
#pragma unroll
  for (int i = 0; i < 32; ++i) { s1 += u[i]; s2 = fmaf(u[i], u[i], s2); }
  ln1[wv * 64 + lane] = s1;
  ln2[wv * 64 + lane] = s2;
  __syncthreads();
  float t1 = 0.f, t2 = 0.f;
#pragma unroll
  for (int w = 0; w < 8; ++w) { t1 += ln1[w * 64 + lane]; t2 += ln2[w * 64 + lane]; }
  float mean = t1 * 0.00390625f;
  float var = t2 * 0.00390625f - mean * mean;
  float rs_ = rsqrtf(var + 1e-5f);
#pragma unroll
  for (int i = 0; i < 32; ++i) u[i] = (u[i] - mean) * rs_ * lng[p0 + i] + lnb[p0 + i];
  // pack normalized u -> ub (safe: GEMM1 done on all waves per LN barrier)
  int ubw = lane * 137 + (p0 >> 1);
#pragma unroll
  for (int i = 0; i < 16; ++i) poolU[ubw + i] = pack2(u[2 * i], u[2 * i + 1]);
  __syncthreads();

  // GEMM2: o[f0..f0+7] per wave, lane=node
  int f0 = __builtin_amdgcn_readfirstlane(wv * 8);
  float o[8];
#pragma unroll
  for (int i = 0; i < 8; ++i) o[i] = 0.f;
  int ubase = lane * 137;
  for (int kc = 0; kc < 256; kc += 4) {
    unsigned u01 = poolU[ubase + (kc >> 1)];
    unsigned u23 = poolU[ubase + (kc >> 1) + 1];
    float a4[4] = {bf_lo(u01), bf_hi(u01), bf_lo(u23), bf_hi(u23)};
#pragma unroll
    for (int q = 0; q < 4; ++q) {
      const float* wrow = w2t + (kc + q) * 64 + f0;
#pragma unroll
      for (int i = 0; i < 8; ++i) o[i] = fmaf(a4[q], wrow[i], o[i]);
    }
  }
#pragma unroll
  for (int i = 0; i < 8; ++i) o[i] += b2[f0 + i];
  __syncthreads();  // all GEMM2 pool reads done
#pragma unroll
  for (int q = 0; q < 2; ++q) {
    float4 w = {o[4 * q], o[4 * q + 1], o[4 * q + 2], o[4 * q + 3]};
    *(float4*)&transf[lane * 68 + f0 + 4 * q] = w;
  }
  __syncthreads();
#pragma unroll
  for (int r = 0; r < 8; ++r) {
    int n = r * 8 + wv;
    int nj = base + n;
    if (nj < nN) out[(size_t)nj * 64 + lane] = transf[n * 68 + lane];
  }
}

extern "C" void kernel_launch(void* const* d_in, const int* in_sizes, int n_in,
                              void* d_out, int out_size, void* d_ws, size_t ws_size,
                              hipStream_t stream) {
  const float* x = (const float*)d_in[0];
  const void* edges = d_in[1];
  const float* conv_wl = (const float*)d_in[2];
  const float* conv_bl = (const float*)d_in[3];
  const float* conv_wr = (const float*)d_in[4];
  const float* ln_g = (const float*)d_in[5];
  const float* ln_b = (const float*)d_in[6];
  const float* adapter_w = (const float*)d_in[7];
  const float* adapter_b = (const float*)d_in[8];
  const float* mlp_w1 = (const float*)d_in[9];
  const float* mlp_b1 = (const float*)d_in[10];
  const float* mlp_lng = (const float*)d_in[11];
  const float* mlp_lnb = (const float*)d_in[12];
  const float* mlp_w2 = (const float*)d_in[13];
  const float* mlp_b2 = (const float*)d_in[14];

  const int N = in_sizes[0] / 64;
  const int E = in_sizes[1] / 2;
  const int NL = in_sizes[2] / (64 * 128);  // 5

  const int Na = (N + 63) & ~63;
  const int Ea = (E + 63) & ~63;
  int* deg = (int*)d_ws;
  int* cursor = deg + Na;
  int* row_start = cursor + Na;
  int* csr_src = row_start + (Na + 64);
  int* flag = csr_src + (Ea + 256);  // pad beyond E for clamped preloads
  int* bsum = flag + 64;
  float* wt_all = (float*)(bsum + 1024);
  float* awt = wt_all + (size_t)NL * 192 * 64;
  float* w1t = awt + 64 * 64;
  float* w2t = w1t + 64 * 256;
  unsigned short* b0 = (unsigned short*)(w2t + 256 * 64);
  unsigned short* b1 = b0 + (size_t)Na * 64;
  float* outf = (float*)d_out;

  hipMemsetAsync(deg, 0, (size_t)N * 4, stream);
  hipMemsetAsync(cursor, 0, (size_t)N * 4, stream);

  detect_idx64<<<1, 64, 0, stream>>>((const unsigned*)edges, flag);
  count_deg<<<1024, 256, 0, stream>>>(edges, flag, deg, E);

  const int nsb = (N + 255) / 256;
  deg_block_sum<<<nsb, 256, 0, stream>>>(deg, bsum, N);
  scan_bsum<<<1, 1024, 0, stream>>>(bsum, nsb);
  scan_final<<<nsb, 256, 0, stream>>>(deg, bsum, row_start, N, E);

  fill_csr<<<1024, 256, 0, stream>>>(edges, flag, row_start, cursor, csr_src, E);

  int prep_tot = NL * 192 * 64 + 64 * 64 + 64 * 256 + 256 * 64;
  prep_weights<<<(prep_tot + 255) / 256, 256, 0, stream>>>(
      conv_wl, conv_wr, adapter_w, mlp_w1, mlp_w2, wt_all, awt, w1t, w2t, NL);

  f32_to_bf16_k<<<1024, 256, 0, stream>>>(x, b0, N * 16);

  const int nb = (N + 63) / 64;
  for (int i = 0; i < NL; ++i) {
    const float* inf = (i == 0) ? x : outf;
    unsigned short* inb = (i & 1) ? b1 : b0;
    unsigned short* outb = (i & 1) ? b0 : b1;
    const float* wt = wt_all + (size_t)i * 192 * 64;
    const float* bl = conv_bl + (size_t)i * 64;
    const float* g = ln_g + (size_t)i * 64;
    const float* b = ln_b + (size_t)i * 64;
    int wf32 = (i == NL - 1) ? 0 : 1;  // last layer: mirror-only (mlp reads bf16)
    if (i == 0) {
      sage_layer<true><<<nb, 256, 0, stream>>>(inf, inb, outf, outb, row_start, csr_src,
                                               wt, awt, bl, adapter_b, g, b, N, wf32);
    } else {
      sage_layer<false><<<nb, 256, 0, stream>>>(inf, inb, outf, outb, row_start, csr_src,
                                                wt, awt, bl, adapter_b, g, b, N, wf32);
    }
  }
  unsigned short* hb_final = ((NL - 1) & 1) ? b0 : b1;
  mlp_head<<<nb, 512, 0, stream>>>(hb_final, outf, w1t, mlp_b1, mlp_lng, mlp_lnb,
                                   w2t, mlp_b2, N);
}

// Round 7
// 455.276 us; speedup vs baseline: 3.6026x; 1.3295x over previous
//
#include <hip/hip_runtime.h>

// SAGEEncoder v7: all GEMMs on bf16 MFMA (16x16x32). Sage: gather (v6 style) +
// MFMA GEMM + in-wave LN. MLP: MFMA GEMM1 -> LN -> MFMA GEMM2. Weights bf16.

#define INFF 3.402823466e38f

typedef __attribute__((ext_vector_type(8))) short bf16x8;
typedef __attribute__((ext_vector_type(4))) float f32x4;

__device__ __forceinline__ unsigned short f2bf(float f) {
  unsigned u = __float_as_uint(f);
  u = (u + 0x7FFFu + ((u >> 16) & 1u)) >> 16;
  return (unsigned short)u;
}
__device__ __forceinline__ unsigned pack2(float a, float b) {
  return (unsigned)f2bf(a) | ((unsigned)f2bf(b) << 16);
}
__device__ __forceinline__ float bf_lo(unsigned u) { return __uint_as_float(u << 16); }
__device__ __forceinline__ float bf_hi(unsigned u) { return __uint_as_float(u & 0xFFFF0000u); }

// ---- edge dtype detection ----
__global__ void detect_idx64(const unsigned* __restrict__ e, int* __restrict__ flag) {
  if (threadIdx.x == 0 && blockIdx.x == 0) {
    int is64 = 1;
    for (int i = 0; i < 32; ++i)
      if (e[2 * i + 1] != 0u) { is64 = 0; break; }
    *flag = is64;
  }
}

__device__ __forceinline__ int edge_val(const void* e, int is64, long long idx) {
  if (is64) return (int)((const long long*)e)[idx];
  return ((const int*)e)[idx];
}

__global__ void count_deg(const void* __restrict__ edges, const int* __restrict__ flag,
                          int* __restrict__ deg, int nE) {
  int is64 = *flag;
  long long E = nE;
  for (int i = blockIdx.x * blockDim.x + threadIdx.x; i < nE; i += gridDim.x * blockDim.x) {
    int dst = edge_val(edges, is64, E + i);
    atomicAdd(&deg[dst], 1);
  }
}

// ---- coalesced 3-phase exclusive scan ----
__global__ void deg_block_sum(const int* __restrict__ deg, int* __restrict__ bsum, int n) {
  __shared__ int w[4];
  int i = blockIdx.x * 256 + threadIdx.x;
  int v = (i < n) ? deg[i] : 0;
#pragma unroll
  for (int off = 32; off >= 1; off >>= 1) v += __shfl_down(v, off);
  if ((threadIdx.x & 63) == 0) w[threadIdx.x >> 6] = v;
  __syncthreads();
  if (threadIdx.x == 0) bsum[blockIdx.x] = w[0] + w[1] + w[2] + w[3];
}

__global__ void scan_bsum(int* __restrict__ bsum, int nb) {
  __shared__ int s[1024];
  int t = threadIdx.x;
  int v = (t < nb) ? bsum[t] : 0;
  s[t] = v;
  __syncthreads();
  for (int off = 1; off < 1024; off <<= 1) {
    int u = (t >= off) ? s[t - off] : 0;
    __syncthreads();
    s[t] += u;
    __syncthreads();
  }
  if (t < nb) bsum[t] = s[t] - v;
}

__global__ void scan_final(const int* __restrict__ deg, const int* __restrict__ bsum,
                           int* __restrict__ row_start, int n, int nE) {
  __shared__ int s[256];
  int t = threadIdx.x;
  int i = blockIdx.x * 256 + t;
  int v = (i < n) ? deg[i] : 0;
  s[t] = v;
  __syncthreads();
  int acc = v;
  for (int off = 1; off < 256; off <<= 1) {
    int u = (t >= off) ? s[t - off] : 0;
    __syncthreads();
    acc += u;
    s[t] = acc;
    __syncthreads();
  }
  if (i < n) row_start[i] = acc - v + bsum[blockIdx.x];
  if (i == n) row_start[n] = nE;
}

__global__ void fill_csr(const void* __restrict__ edges, const int* __restrict__ flag,
                         const int* __restrict__ row_start, int* __restrict__ cursor,
                         int* __restrict__ csr_src, int nE) {
  int is64 = *flag;
  long long E = nE;
  for (int i = blockIdx.x * blockDim.x + threadIdx.x; i < nE; i += gridDim.x * blockDim.x) {
    int src = edge_val(edges, is64, i);
    int dst = edge_val(edges, is64, E + i);
    int p = atomicAdd(&cursor[dst], 1);
    csr_src[row_start[dst] + p] = src;
  }
}

// ---- bf16 weight conversion (no transposes: B-frag wants W[n][k], k-contiguous) ----
__global__ void prep_weights_bf(const float* __restrict__ wl, const float* __restrict__ wr,
                                const float* __restrict__ aw, const float* __restrict__ w1,
                                const float* __restrict__ w2,
                                unsigned short* __restrict__ wcatb,
                                unsigned short* __restrict__ awb,
                                unsigned short* __restrict__ w1b,
                                unsigned short* __restrict__ w2b, int nl) {
  int i = blockIdx.x * 256 + threadIdx.x;
  int tot = nl * 64 * 192;
  if (i < tot) {
    int l = i / (64 * 192), r = i % (64 * 192), f = r / 192, k = r % 192;
    float v = (k < 128) ? wl[l * 8192 + f * 128 + k] : wr[l * 4096 + f * 64 + (k - 128)];
    wcatb[i] = f2bf(v);
  } else {
    int j = i - tot;
    if (j < 4096) awb[j] = f2bf(aw[j]);
    else if (j < 4096 + 16384) w1b[j - 4096] = f2bf(w1[j - 4096]);
    else if (j < 4096 + 32768) w2b[j - 20480] = f2bf(w2[j - 20480]);
  }
}

__global__ void f32_to_bf16_k(const float* __restrict__ in, unsigned short* __restrict__ out,
                              int n4) {
  int stride = gridDim.x * blockDim.x;
  for (int i = blockIdx.x * blockDim.x + threadIdx.x; i < n4; i += stride) {
    float4 v = ((const float4*)in)[i];
    ushort4 o;
    o.x = f2bf(v.x); o.y = f2bf(v.y); o.z = f2bf(v.z); o.w = f2bf(v.w);
    ((ushort4*)out)[i] = o;
  }
}

// ---- fused SAGE layer: v6 gather + MFMA GEMM + in-wave LN ----
// Block: 256 threads (4 waves), 64 nodes. aggU[64][100]dw rows (16B-aligned,
// 2-way banks): bf16 [max(64)|mean(64)|x(64)|pad].
template <bool FIRST>
__global__ __launch_bounds__(256, 5) void sage_layer(
    const float* __restrict__ inf, const unsigned short* __restrict__ inb,
    float* __restrict__ outf, unsigned short* __restrict__ outb,
    const int* __restrict__ row_start, const int* __restrict__ csr_src,
    const unsigned short* __restrict__ wcat,  // [64][192] bf16
    const unsigned short* __restrict__ awb,   // [64][64] bf16
    const float* __restrict__ bl, const float* __restrict__ ab,
    const float* __restrict__ lng, const float* __restrict__ lnb,
    int nN, int wf32) {
  __shared__ unsigned aggU[64 * 100];

  int t = threadIdx.x;
  int wv = __builtin_amdgcn_readfirstlane(t >> 6);
  int lane = t & 63;
  int g_lane = lane >> 4;
  int fq4 = (lane & 15) * 4;
  int foff = fq4 * 2;
  int base = blockIdx.x * 64;
  int wn0 = base + wv * 16;

  // row bounds: one vector load + readlane/shfl
  int rlv = row_start[min(wn0 + min(lane, 16), nN)];
  int rs[17];
#pragma unroll
  for (int i = 0; i <= 16; ++i) rs[i] = __builtin_amdgcn_readlane(rlv, i);

  int offL[4], dgL[4], dgmL[4];
#pragma unroll
  for (int G = 0; G < 4; ++G) {
    int a_ = __shfl(rlv, 4 * G + g_lane);
    int b_ = __shfl(rlv, 4 * G + g_lane + 1);
    offL[G] = a_ - rs[4 * G];
    dgL[G] = b_ - a_;
    dgmL[G] = max(dgL[G] - 1, 0);
  }

  int ivA[4], ivB[4];
#pragma unroll
  for (int G = 0; G < 4; ++G) {
    int Eg = rs[4 * G];
    int lenm1 = max(rs[4 * G + 4] - Eg - 1, 0);
    ivA[G] = min((unsigned)csr_src[Eg + min(lane, lenm1)], (unsigned)(nN - 1));
    ivB[G] = min((unsigned)csr_src[Eg + min(lane + 64, lenm1)], (unsigned)(nN - 1));
  }

  // stage self rows (fp32 -> bf16, cols 128..191)
#pragma unroll
  for (int R = 0; R < 4; ++R) {
    int nloc = R * 4 + g_lane;
    int nj = wn0 + nloc;
    bool ok = nj < nN;
    unsigned njc = min((unsigned)nj, (unsigned)(nN - 1));
    float4 xv = *(const float4*)(inf + (size_t)njc * 64u + fq4);
    if (!ok) xv = make_float4(0.f, 0.f, 0.f, 0.f);
    int rowU = (wv * 16 + nloc) * 100;
    aggU[rowU + 64 + (fq4 >> 1)] = pack2(xv.x, xv.y);
    aggU[rowU + 64 + (fq4 >> 1) + 1] = pack2(xv.z, xv.w);
  }

  // gather (bf16 mirror): 4 nodes lockstep, 16-edge batches
#pragma unroll
  for (int G = 0; G < 4; ++G) {
    int Eg = rs[4 * G];
    int len = rs[4 * G + 4] - Eg;
    int d0 = rs[4 * G + 1] - rs[4 * G + 0], d1 = rs[4 * G + 2] - rs[4 * G + 1];
    int d2 = rs[4 * G + 3] - rs[4 * G + 2], d3 = rs[4 * G + 4] - rs[4 * G + 3];
    int mm = max(max(d0, d1), max(d2, d3));
    int offl = offL[G], dgl = dgL[G], dgml = dgmL[G];
    float4 mx = make_float4(-INFF, -INFF, -INFF, -INFF);
    float4 sm = make_float4(0.f, 0.f, 0.f, 0.f);

    if (len <= 64) {
      for (int tt = 0; tt < mm; tt += 16) {
        uint2 v[16];
#pragma unroll
        for (int u = 0; u < 16; ++u) {
          int p = offl + min(tt + u, dgml);
          int si = __shfl(ivA[G], p);
          v[u] = *(const uint2*)((const char*)inb + ((si << 7) + foff));
        }
#pragma unroll
        for (int u = 0; u < 16; ++u) {
          float f0 = bf_lo(v[u].x), f1 = bf_hi(v[u].x);
          float f2 = bf_lo(v[u].y), f3 = bf_hi(v[u].y);
          float m = (tt + u < dgl) ? 1.f : 0.f;
          mx.x = fmaxf(mx.x, f0); mx.y = fmaxf(mx.y, f1);
          mx.z = fmaxf(mx.z, f2); mx.w = fmaxf(mx.w, f3);
          sm.x = fmaf(f0, m, sm.x); sm.y = fmaf(f1, m, sm.y);
          sm.z = fmaf(f2, m, sm.z); sm.w = fmaf(f3, m, sm.w);
        }
      }
    } else if (len <= 128) {
      for (int tt = 0; tt < mm; tt += 8) {
        uint2 v[8];
#pragma unroll
        for (int u = 0; u < 8; ++u) {
          int p = offl + min(tt + u, dgml);
          int a = __shfl(ivA[G], p & 63);
          int b = __shfl(ivB[G], p & 63);
          int si = (p < 64) ? a : b;
          v[u] = *(const uint2*)((const char*)inb + ((si << 7) + foff));
        }
#pragma unroll
        for (int u = 0; u < 8; ++u) {
          float f0 = bf_lo(v[u].x), f1 = bf_hi(v[u].x);
          float f2 = bf_lo(v[u].y), f3 = bf_hi(v[u].y);
          float m = (tt + u < dgl) ? 1.f : 0.f;
          mx.x = fmaxf(mx.x, f0); mx.y = fmaxf(mx.y, f1);
          mx.z = fmaxf(mx.z, f2); mx.w = fmaxf(mx.w, f3);
          sm.x = fmaf(f0, m, sm.x); sm.y = fmaf(f1, m, sm.y);
          sm.z = fmaf(f2, m, sm.z); sm.w = fmaf(f3, m, sm.w);
        }
      }
    } else {
      for (int tt = 0; tt < mm; tt += 4) {
        uint2 v[4];
#pragma unroll
        for (int u = 0; u < 4; ++u) {
          int p = offl + min(tt + u, dgml);
          unsigned si = min((unsigned)csr_src[Eg + p], (unsigned)(nN - 1));
          v[u] = *(const uint2*)((const char*)inb + (((int)si << 7) + foff));
        }
#pragma unroll
        for (int u = 0; u < 4; ++u) {
          float f0 = bf_lo(v[u].x), f1 = bf_hi(v[u].x);
          float f2 = bf_lo(v[u].y), f3 = bf_hi(v[u].y);
          float m = (tt + u < dgl) ? 1.f : 0.f;
          mx.x = fmaxf(mx.x, f0); mx.y = fmaxf(mx.y, f1);
          mx.z = fmaxf(mx.z, f2); mx.w = fmaxf(mx.w, f3);
          sm.x = fmaf(f0, m, sm.x); sm.y = fmaf(f1, m, sm.y);
          sm.z = fmaf(f2, m, sm.z); sm.w = fmaf(f3, m, sm.w);
        }
      }
    }

    int rowU = (wv * 16 + G * 4 + g_lane) * 100;
    float ok = (dgl > 0) ? 1.f : 0.f;
    float r = 1.f / (float)max(dgl, 1);
    aggU[rowU + (fq4 >> 1)] = pack2(ok * mx.x, ok * mx.y);
    aggU[rowU + (fq4 >> 1) + 1] = pack2(ok * mx.z, ok * mx.w);
    aggU[rowU + 32 + (fq4 >> 1)] = pack2(sm.x * r, sm.y * r);
    aggU[rowU + 32 + (fq4 >> 1) + 1] = pack2(sm.z * r, sm.w * r);
  }
  __syncthreads();

  // ---- MFMA GEMM: wave = node-tile nt=wv; acc[ft] covers f-tiles 0..3 ----
  int nt = wv;
  int ml = lane & 15, gq = lane >> 4;
  bf16x8 afr[6];
  const char* arow = (const char*)aggU + (size_t)(nt * 16 + ml) * 400;
#pragma unroll
  for (int ks = 0; ks < 6; ++ks)
    afr[ks] = *(const bf16x8*)(arow + ks * 64 + gq * 16);

  f32x4 acc[4], accr[4];
#pragma unroll
  for (int ft = 0; ft < 4; ++ft) {
    acc[ft] = (f32x4){0.f, 0.f, 0.f, 0.f};
    const char* brow = (const char*)wcat + (size_t)(ft * 16 + ml) * 384;
#pragma unroll
    for (int ks = 0; ks < 6; ++ks) {
      bf16x8 b = *(const bf16x8*)(brow + ks * 64 + gq * 16);
      acc[ft] = __builtin_amdgcn_mfma_f32_16x16x32_bf16(afr[ks], b, acc[ft], 0, 0, 0);
    }
    if (FIRST) {
      accr[ft] = (f32x4){0.f, 0.f, 0.f, 0.f};
      const char* crow = (const char*)awb + (size_t)(ft * 16 + ml) * 128;
#pragma unroll
      for (int k2 = 0; k2 < 2; ++k2) {
        bf16x8 b = *(const bf16x8*)(crow + k2 * 64 + gq * 16);
        accr[ft] = __builtin_amdgcn_mfma_f32_16x16x32_bf16(afr[4 + k2], b, accr[ft], 0, 0, 0);
      }
    }
  }

  // ---- epilogue: bias, in-wave LN, residual, SiLU, store ----
  // D layout: f = ft*16 + ml, node = nt*16 + gq*4 + reg
  float blv[4], gv[4], bvv[4], abv[4];
#pragma unroll
  for (int ft = 0; ft < 4; ++ft) {
    blv[ft] = bl[ft * 16 + ml];
    gv[ft] = lng[ft * 16 + ml];
    bvv[ft] = lnb[ft * 16 + ml];
    if (FIRST) abv[ft] = ab[ft * 16 + ml];
  }
  float v[4][4];
  float s1[4] = {0.f, 0.f, 0.f, 0.f}, s2[4] = {0.f, 0.f, 0.f, 0.f};
#pragma unroll
  for (int ft = 0; ft < 4; ++ft)
#pragma unroll
    for (int reg = 0; reg < 4; ++reg) {
      float a = acc[ft][reg] + blv[ft];
      v[ft][reg] = a;
      s1[reg] += a;
      s2[reg] = fmaf(a, a, s2[reg]);
    }
#pragma unroll
  for (int m = 1; m < 16; m <<= 1)
#pragma unroll
    for (int reg = 0; reg < 4; ++reg) {
      s1[reg] += __shfl_xor(s1[reg], m);
      s2[reg] += __shfl_xor(s2[reg], m);
    }

#pragma unroll
  for (int reg = 0; reg < 4; ++reg) {
    float mean = s1[reg] * 0.015625f;
    float var = s2[reg] * 0.015625f - mean * mean;
    float rs_ = rsqrtf(var + 1e-5f);
    int nj = base + nt * 16 + gq * 4 + reg;
    unsigned njc = min((unsigned)nj, (unsigned)(nN - 1));
    bool ok = nj < nN;
#pragma unroll
    for (int ft = 0; ft < 4; ++ft) {
      float res = FIRST ? (accr[ft][reg] + abv[ft])
                        : inf[(size_t)njc * 64 + ft * 16 + ml];
      float y = (v[ft][reg] - mean) * rs_ * gv[ft] + bvv[ft] + res;
      float h = y / (1.f + __expf(-y));
      if (ok) {
        if (wf32) outf[(size_t)nj * 64 + ft * 16 + ml] = h;
        outb[(size_t)nj * 64 + ft * 16 + ml] = f2bf(h);
      }
    }
  }
}

// ---- MLP head: MFMA GEMM1 -> SiLU -> LN(256) -> MFMA GEMM2 ----
// Block: 512 threads (8 waves), 64 nodes. wave: nt=wv&3, p-half ph=wv>>2.
__global__ __launch_bounds__(512) void mlp_head(
    const unsigned short* __restrict__ inb, float* __restrict__ out,
    const unsigned short* __restrict__ w1b,  // [256][64] bf16
    const float* __restrict__ b1,
    const float* __restrict__ lng, const float* __restrict__ lnb,
    const unsigned short* __restrict__ w2b,  // [64][256] bf16
    const float* __restrict__ b2, int nN) {
  __shared__ unsigned short up[64 * 264];  // u' bf16, 528B rows (16B-aligned)
  __shared__ float ln1[128], ln2[128];

  int t = threadIdx.x;
  int wv = __builtin_amdgcn_readfirstlane(t >> 6);
  int lane = t & 63;
  int ml = lane & 15, gq = lane >> 4;
  int base = blockIdx.x * 64;
  int nt = wv & 3, ph = wv >> 2;

  // GEMM1: A from global bf16 mirror, B = w1b rows
  int nodeA = min(base + nt * 16 + ml, nN - 1);
  const char* arow = (const char*)inb + (size_t)nodeA * 128;
  bf16x8 a0 = *(const bf16x8*)(arow + gq * 16);
  bf16x8 a1 = *(const bf16x8*)(arow + 64 + gq * 16);

  f32x4 acc[8];
#pragma unroll
  for (int pt = 0; pt < 8; ++pt) {
    int p0 = ph * 128 + pt * 16;
    const char* brow = (const char*)w1b + (size_t)(p0 + ml) * 128;
    bf16x8 b0 = *(const bf16x8*)(brow + gq * 16);
    bf16x8 b1f = *(const bf16x8*)(brow + 64 + gq * 16);
    f32x4 c = (f32x4){0.f, 0.f, 0.f, 0.f};
    c = __builtin_amdgcn_mfma_f32_16x16x32_bf16(a0, b0, c, 0, 0, 0);
    c = __builtin_amdgcn_mfma_f32_16x16x32_bf16(a1, b1f, c, 0, 0, 0);
    acc[pt] = c;
  }

  // bias + SiLU (in place), LN partial sums per reg
  float s1[4] = {0.f, 0.f, 0.f, 0.f}, s2[4] = {0.f, 0.f, 0.f, 0.f};
#pragma unroll
  for (int pt = 0; pt < 8; ++pt) {
    float bb = b1[ph * 128 + pt * 16 + ml];
#pragma unroll
    for (int reg = 0; reg < 4; ++reg) {
      float u = acc[pt][reg] + bb;
      u = u / (1.f + __expf(-u));
      acc[pt][reg] = u;
      s1[reg] += u;
      s2[reg] = fmaf(u, u, s2[reg]);
    }
  }
#pragma unroll
  for (int m = 1; m < 16; m <<= 1)
#pragma unroll
    for (int reg = 0; reg < 4; ++reg) {
      s1[reg] += __shfl_xor(s1[reg], m);
      s2[reg] += __shfl_xor(s2[reg], m);
    }
  if (ml == 0) {
#pragma unroll
    for (int reg = 0; reg < 4; ++reg) {
      ln1[wv * 16 + gq * 4 + reg] = s1[reg];
      ln2[wv * 16 + gq * 4 + reg] = s2[reg];
    }
  }
  __syncthreads();
  float mean[4], rsv[4];
#pragma unroll
  for (int reg = 0; reg < 4; ++reg) {
    float t1 = s1[reg] + ln1[(wv ^ 4) * 16 + gq * 4 + reg];
    float t2 = s2[reg] + ln2[(wv ^ 4) * 16 + gq * 4 + reg];
    float mn = t1 * 0.00390625f;
    float var = t2 * 0.00390625f - mn * mn;
    mean[reg] = mn;
    rsv[reg] = rsqrtf(var + 1e-5f);
  }
  // normalize + stage u' bf16
#pragma unroll
  for (int pt = 0; pt < 8; ++pt) {
    int p = ph * 128 + pt * 16 + ml;
    float g = lng[p], bb = lnb[p];
#pragma unroll
    for (int reg = 0; reg < 4; ++reg) {
      float val = (acc[pt][reg] - mean[reg]) * rsv[reg] * g + bb;
      up[(nt * 16 + gq * 4 + reg) * 264 + p] = f2bf(val);
    }
  }
  __syncthreads();

  // GEMM2: A from up (K=256), B = w2b rows; wave covers 2 f-tiles
  f32x4 o0 = (f32x4){0.f, 0.f, 0.f, 0.f};
  f32x4 o1 = (f32x4){0.f, 0.f, 0.f, 0.f};
  const char* urow = (const char*)up + (size_t)(nt * 16 + ml) * 528;
  int fA = (ph * 2 + 0) * 16, fB = (ph * 2 + 1) * 16;
  const char* browA = (const char*)w2b + (size_t)(fA + ml) * 512;
  const char* browB = (const char*)w2b + (size_t)(fB + ml) * 512;
#pragma unroll
  for (int ks = 0; ks < 8; ++ks) {
    bf16x8 a = *(const bf16x8*)(urow + ks * 64 + gq * 16);
    bf16x8 bA = *(const bf16x8*)(browA + ks * 64 + gq * 16);
    bf16x8 bB = *(const bf16x8*)(browB + ks * 64 + gq * 16);
    o0 = __builtin_amdgcn_mfma_f32_16x16x32_bf16(a, bA, o0, 0, 0, 0);
    o1 = __builtin_amdgcn_mfma_f32_16x16x32_bf16(a, bB, o1, 0, 0, 0);
  }
  float b2A = b2[fA + ml], b2B = b2[fB + ml];
#pragma unroll
  for (int reg = 0; reg < 4; ++reg) {
    int nj = base + nt * 16 + gq * 4 + reg;
    if (nj < nN) {
      out[(size_t)nj * 64 + fA + ml] = o0[reg] + b2A;
      out[(size_t)nj * 64 + fB + ml] = o1[reg] + b2B;
    }
  }
}

extern "C" void kernel_launch(void* const* d_in, const int* in_sizes, int n_in,
                              void* d_out, int out_size, void* d_ws, size_t ws_size,
                              hipStream_t stream) {
  const float* x = (const float*)d_in[0];
  const void* edges = d_in[1];
  const float* conv_wl = (const float*)d_in[2];
  const float* conv_bl = (const float*)d_in[3];
  const float* conv_wr = (const float*)d_in[4];
  const float* ln_g = (const float*)d_in[5];
  const float* ln_b = (const float*)d_in[6];
  const float* adapter_w = (const float*)d_in[7];
  const float* adapter_b = (const float*)d_in[8];
  const float* mlp_w1 = (const float*)d_in[9];
  const float* mlp_b1 = (const float*)d_in[10];
  const float* mlp_lng = (const float*)d_in[11];
  const float* mlp_lnb = (const float*)d_in[12];
  const float* mlp_w2 = (const float*)d_in[13];
  const float* mlp_b2 = (const float*)d_in[14];

  const int N = in_sizes[0] / 64;
  const int E = in_sizes[1] / 2;
  const int NL = in_sizes[2] / (64 * 128);  // 5

  const int Na = (N + 63) & ~63;
  const int Ea = (E + 63) & ~63;
  int* deg = (int*)d_ws;
  int* cursor = deg + Na;
  int* row_start = cursor + Na;
  int* csr_src = row_start + (Na + 64);
  int* flag = csr_src + (Ea + 256);
  int* bsum = flag + 64;
  unsigned short* wcatb = (unsigned short*)(bsum + 1024);
  unsigned short* awb = wcatb + (size_t)NL * 64 * 192;
  unsigned short* w1b = awb + 4096;
  unsigned short* w2b = w1b + 16384;
  unsigned short* b0 = w2b + 16384;
  unsigned short* b1m = b0 + (size_t)Na * 64;
  float* outf = (float*)d_out;

  hipMemsetAsync(deg, 0, (size_t)N * 4, stream);
  hipMemsetAsync(cursor, 0, (size_t)N * 4, stream);

  detect_idx64<<<1, 64, 0, stream>>>((const unsigned*)edges, flag);
  count_deg<<<1024, 256, 0, stream>>>(edges, flag, deg, E);

  const int nsb = (N + 255) / 256;
  deg_block_sum<<<nsb, 256, 0, stream>>>(deg, bsum, N);
  scan_bsum<<<1, 1024, 0, stream>>>(bsum, nsb);
  scan_final<<<nsb, 256, 0, stream>>>(deg, bsum, row_start, N, E);

  fill_csr<<<1024, 256, 0, stream>>>(edges, flag, row_start, cursor, csr_src, E);

  int prep_tot = NL * 64 * 192 + 4096 + 16384 + 16384;
  prep_weights_bf<<<(prep_tot + 255) / 256, 256, 0, stream>>>(
      conv_wl, conv_wr, adapter_w, mlp_w1, mlp_w2, wcatb, awb, w1b, w2b, NL);

  f32_to_bf16_k<<<1024, 256, 0, stream>>>(x, b0, N * 16);

  const int nb = (N + 63) / 64;
  for (int i = 0; i < NL; ++i) {
    const float* inf = (i == 0) ? x : outf;
    unsigned short* inb = (i & 1) ? b1m : b0;
    unsigned short* outb = (i & 1) ? b0 : b1m;
    const unsigned short* wc = wcatb + (size_t)i * 64 * 192;
    const float* bl = conv_bl + (size_t)i * 64;
    const float* g = ln_g + (size_t)i * 64;
    const float* b = ln_b + (size_t)i * 64;
    int wf32 = (i == NL - 1) ? 0 : 1;
    if (i == 0) {
      sage_layer<true><<<nb, 256, 0, stream>>>(inf, inb, outf, outb, row_start, csr_src,
                                               wc, awb, bl, adapter_b, g, b, N, wf32);
    } else {
      sage_layer<false><<<nb, 256, 0, stream>>>(inf, inb, outf, outb, row_start, csr_src,
                                                wc, awb, bl, adapter_b, g, b, N, wf32);
    }
  }
  unsigned short* hb_final = ((NL - 1) & 1) ? b0 : b1m;
  mlp_head<<<nb, 512, 0, stream>>>(hb_final, outf, w1b, mlp_b1, mlp_lng, mlp_lnb,
                                   w2b, mlp_b2, N);
}